// Round 1
// baseline (5193.759 us; speedup 1.0000x reference)
//
#include <hip/hip_runtime.h>

#define N_NODES 50000
#define N_EDGES 800000
#define NODE_DIM 128
#define EDGE_DIM 64
#define HIDDEN 128
#define OUT_DIM 64

// ---------------------------------------------------------------------------
// Scatter raw 128-float rows: acc[col[e]] += feat[row[e]]; optional deg count.
// 32 lanes per edge (one float4 each), 8 edges per 256-thread block.
// ---------------------------------------------------------------------------
__global__ __launch_bounds__(256) void scatter_node(
    const float* __restrict__ feat, const int* __restrict__ row,
    const int* __restrict__ col, float* __restrict__ acc,
    float* __restrict__ deg, int n_edges)
{
    int e = (blockIdx.x << 3) + (threadIdx.x >> 5);
    if (e >= n_edges) return;
    int lane = threadIdx.x & 31;
    int r = row[e];
    int c = col[e];
    float4 v = ((const float4*)(feat + (size_t)r * 128))[lane];
    float* d = acc + (size_t)c * 128 + lane * 4;
    unsafeAtomicAdd(d + 0, v.x);
    unsafeAtomicAdd(d + 1, v.y);
    unsafeAtomicAdd(d + 2, v.z);
    unsafeAtomicAdd(d + 3, v.w);
    if (deg != nullptr && lane == 0) unsafeAtomicAdd(deg + c, 1.0f);
}

// ---------------------------------------------------------------------------
// Edge path fused: G[col[mcol[e]]] += ef[mrow[e]] (64 floats); cntm[d] += 1.
// 16 lanes per edge, 16 edges per block.
// ---------------------------------------------------------------------------
__global__ __launch_bounds__(256) void scatter_edge(
    const float* __restrict__ ef, const int* __restrict__ mrow,
    const int* __restrict__ mcol, const int* __restrict__ col,
    float* __restrict__ G, float* __restrict__ cntm, int n_edges)
{
    int e = (blockIdx.x << 4) + (threadIdx.x >> 4);
    if (e >= n_edges) return;
    int lane = threadIdx.x & 15;
    int se = mrow[e];
    int de = mcol[e];
    int d = col[de];
    float4 v = ((const float4*)(ef + (size_t)se * 64))[lane];
    float* g = G + (size_t)d * 64 + lane * 4;
    unsafeAtomicAdd(g + 0, v.x);
    unsafeAtomicAdd(g + 1, v.y);
    unsafeAtomicAdd(g + 2, v.z);
    unsafeAtomicAdd(g + 3, v.w);
    if (lane == 0) unsafeAtomicAdd(cntm + d, 1.0f);
}

// ---------------------------------------------------------------------------
// X = relu(A @ W + deg⊗bias).  A: (M,128), W: (128,128) row-major.
// 8 rows per block; W staged in LDS in two 64-row chunks (36 KB LDS total).
// ---------------------------------------------------------------------------
__global__ __launch_bounds__(256) void gemm128_relu(
    const float* __restrict__ A, const float* __restrict__ W,
    const float* __restrict__ bias, const float* __restrict__ deg,
    float* __restrict__ X, int M)
{
    __shared__ float Ws[64 * 128];   // 32 KB
    __shared__ float As[8][128];     // 4 KB
    int r0 = blockIdx.x * 8;
    for (int i = threadIdx.x; i < 8 * 32; i += 256) {
        int rr = i >> 5, cc = i & 31;
        int gr = r0 + rr;
        float4 v = make_float4(0.f, 0.f, 0.f, 0.f);
        if (gr < M) v = ((const float4*)(A + (size_t)gr * 128))[cc];
        ((float4*)(&As[rr][0]))[cc] = v;
    }
    float acc0 = 0.f, acc1 = 0.f, acc2 = 0.f, acc3 = 0.f;
    int rl = threadIdx.x >> 5;   // 0..7
    int cg = threadIdx.x & 31;   // cols 4cg..4cg+3
    for (int kb = 0; kb < 2; kb++) {
        __syncthreads();
        for (int i = threadIdx.x; i < 64 * 32; i += 256)
            ((float4*)Ws)[i] = ((const float4*)(W + kb * 64 * 128))[i];
        __syncthreads();
        #pragma unroll 8
        for (int k = 0; k < 64; k++) {
            float a = As[rl][kb * 64 + k];
            float4 w = *(const float4*)(&Ws[k * 128 + cg * 4]);
            acc0 = fmaf(a, w.x, acc0);
            acc1 = fmaf(a, w.y, acc1);
            acc2 = fmaf(a, w.z, acc2);
            acc3 = fmaf(a, w.w, acc3);
        }
    }
    int r = r0 + rl;
    if (r < M) {
        float dg = deg[r];
        float4 bb = ((const float4*)bias)[cg];
        float4 o;
        o.x = fmaxf(fmaf(dg, bb.x, acc0), 0.0f);
        o.y = fmaxf(fmaf(dg, bb.y, acc1), 0.0f);
        o.z = fmaxf(fmaf(dg, bb.z, acc2), 0.0f);
        o.w = fmaxf(fmaf(dg, bb.w, acc3), 0.0f);
        ((float4*)(X + (size_t)r * 128))[cg] = o;
    }
}

// ---------------------------------------------------------------------------
// Wcomb = We @ Wfc[128:256], bvec = be @ Wfc[128:256]
// ---------------------------------------------------------------------------
__global__ __launch_bounds__(256) void precompute_wcomb(
    const float* __restrict__ We, const float* __restrict__ be,
    const float* __restrict__ Wfc, float* __restrict__ Wcomb,
    float* __restrict__ bvec)
{
    int idx = blockIdx.x * 256 + threadIdx.x;
    if (idx < 64 * 64) {
        int k = idx >> 6, c = idx & 63;
        float s = 0.f;
        for (int h = 0; h < 128; h++)
            s = fmaf(We[k * 128 + h], Wfc[(128 + h) * 64 + c], s);
        Wcomb[idx] = s;
    } else if (idx < 64 * 64 + 64) {
        int c = idx - 64 * 64;
        float s = 0.f;
        for (int h = 0; h < 128; h++)
            s = fmaf(be[h], Wfc[(128 + h) * 64 + c], s);
        bvec[c] = s;
    }
}

// ---------------------------------------------------------------------------
// out = (X2 + A3) @ Wfc[0:128] + G @ Wcomb + cntm⊗bvec + bfc
// 16 rows per block; weights in LDS (60 KB total).
// ---------------------------------------------------------------------------
__global__ __launch_bounds__(256) void final_gemm(
    const float* __restrict__ X2, const float* __restrict__ A3,
    const float* __restrict__ G, const float* __restrict__ cntm,
    const float* __restrict__ Wfc, const float* __restrict__ Wcomb,
    const float* __restrict__ bvec, const float* __restrict__ bfc,
    float* __restrict__ out, int M)
{
    __shared__ float Wt[128 * 64];   // 32 KB — top half of Wfc
    __shared__ float Wc[64 * 64];    // 16 KB
    __shared__ float Ss[16][128];    // 8 KB — x2 + agg_neighbors rows
    __shared__ float Gs[16][64];     // 4 KB
    int r0 = blockIdx.x * 16;
    for (int i = threadIdx.x; i < 128 * 16; i += 256)
        ((float4*)Wt)[i] = ((const float4*)Wfc)[i];
    for (int i = threadIdx.x; i < 64 * 16; i += 256)
        ((float4*)Wc)[i] = ((const float4*)Wcomb)[i];
    for (int i = threadIdx.x; i < 16 * 32; i += 256) {
        int rr = i >> 5, cc = i & 31;
        int gr = r0 + rr;
        float4 v = make_float4(0.f, 0.f, 0.f, 0.f);
        if (gr < M) {
            float4 a = ((const float4*)(X2 + (size_t)gr * 128))[cc];
            float4 b = ((const float4*)(A3 + (size_t)gr * 128))[cc];
            v = make_float4(a.x + b.x, a.y + b.y, a.z + b.z, a.w + b.w);
        }
        ((float4*)(&Ss[rr][0]))[cc] = v;
    }
    for (int i = threadIdx.x; i < 16 * 16; i += 256) {
        int rr = i >> 4, cc = i & 15;
        int gr = r0 + rr;
        float4 v = make_float4(0.f, 0.f, 0.f, 0.f);
        if (gr < M) v = ((const float4*)(G + (size_t)gr * 64))[cc];
        ((float4*)(&Gs[rr][0]))[cc] = v;
    }
    __syncthreads();
    int rl = threadIdx.x >> 4;   // 0..15
    int cg = threadIdx.x & 15;   // cols 4cg..4cg+3
    int r = r0 + rl;
    float cnt = (r < M) ? cntm[r] : 0.0f;
    float4 bv = ((const float4*)bvec)[cg];
    float4 bf = ((const float4*)bfc)[cg];
    float a0 = fmaf(cnt, bv.x, bf.x);
    float a1 = fmaf(cnt, bv.y, bf.y);
    float a2 = fmaf(cnt, bv.z, bf.z);
    float a3 = fmaf(cnt, bv.w, bf.w);
    #pragma unroll 4
    for (int k = 0; k < 128; k++) {
        float a = Ss[rl][k];
        float4 w = *(const float4*)(&Wt[k * 64 + cg * 4]);
        a0 = fmaf(a, w.x, a0);
        a1 = fmaf(a, w.y, a1);
        a2 = fmaf(a, w.z, a2);
        a3 = fmaf(a, w.w, a3);
    }
    #pragma unroll 4
    for (int k = 0; k < 64; k++) {
        float g = Gs[rl][k];
        float4 w = *(const float4*)(&Wc[k * 64 + cg * 4]);
        a0 = fmaf(g, w.x, a0);
        a1 = fmaf(g, w.y, a1);
        a2 = fmaf(g, w.z, a2);
        a3 = fmaf(g, w.w, a3);
    }
    if (r < M)
        ((float4*)(out + (size_t)r * 64))[cg] = make_float4(a0, a1, a2, a3);
}

extern "C" void kernel_launch(void* const* d_in, const int* in_sizes, int n_in,
                              void* d_out, int out_size, void* d_ws, size_t ws_size,
                              hipStream_t stream)
{
    const float* nf  = (const float*)d_in[0];
    const int*   ei  = (const int*)d_in[1];
    const float* ef  = (const float*)d_in[2];
    const int*   emi = (const int*)d_in[3];
    const float* W1  = (const float*)d_in[4];
    const float* b1  = (const float*)d_in[5];
    const float* W2  = (const float*)d_in[6];
    const float* b2  = (const float*)d_in[7];
    const float* We  = (const float*)d_in[8];
    const float* be  = (const float*)d_in[9];
    const float* Wfc = (const float*)d_in[10];
    const float* bfc = (const float*)d_in[11];

    const int* row  = ei;
    const int* col  = ei + N_EDGES;
    const int* mrow = emi;
    const int* mcol = emi + N_EDGES;

    // workspace layout (floats):
    //   bufA : N_NODES*128  (A1 -> A2 -> A3/agg_neighbors, zeroed each phase)
    //   bufX : N_NODES*128  (x1, then x2 overwrites it)
    //   G    : N_NODES*64
    //   deg  : N_NODES
    //   cntm : N_NODES
    //   Wcomb: 64*64, bvec: 64
    float* ws    = (float*)d_ws;
    float* bufA  = ws;
    float* bufX  = bufA + (size_t)N_NODES * HIDDEN;
    float* G     = bufX + (size_t)N_NODES * HIDDEN;
    float* deg   = G + (size_t)N_NODES * EDGE_DIM;
    float* cntm  = deg + N_NODES;
    float* Wcomb = cntm + N_NODES;
    float* bvec  = Wcomb + 64 * 64;

    const size_t nodeBytes = (size_t)N_NODES * HIDDEN * sizeof(float);

    // zero accumulators (G..cntm contiguous)
    hipMemsetAsync(bufA, 0, nodeBytes, stream);
    hipMemsetAsync(G, 0, ((size_t)N_NODES * EDGE_DIM + 2 * (size_t)N_NODES) * sizeof(float), stream);

    precompute_wcomb<<<17, 256, 0, stream>>>(We, be, Wfc, Wcomb, bvec);

    // layer 1: A1[col] += nf[row]; deg[col] += 1; x1 = relu(A1@W1 + deg⊗b1)
    scatter_node<<<N_EDGES / 8, 256, 0, stream>>>(nf, row, col, bufA, deg, N_EDGES);
    gemm128_relu<<<(N_NODES + 7) / 8, 256, 0, stream>>>(bufA, W1, b1, deg, bufX, N_NODES);

    // layer 2: A2[col] += x1[row]; x2 = relu(A2@W2 + deg⊗b2)  (x2 overwrites x1)
    hipMemsetAsync(bufA, 0, nodeBytes, stream);
    scatter_node<<<N_EDGES / 8, 256, 0, stream>>>(bufX, row, col, bufA, nullptr, N_EDGES);
    gemm128_relu<<<(N_NODES + 7) / 8, 256, 0, stream>>>(bufA, W2, b2, deg, bufX, N_NODES);

    // agg_neighbors: A3[col] += x2[row]
    hipMemsetAsync(bufA, 0, nodeBytes, stream);
    scatter_node<<<N_EDGES / 8, 256, 0, stream>>>(bufX, row, col, bufA, nullptr, N_EDGES);

    // edge path: G[col[mcol]] += ef[mrow]; cntm += 1
    scatter_edge<<<N_EDGES / 16, 256, 0, stream>>>(ef, mrow, mcol, col, G, cntm, N_EDGES);

    // epilogue: out = (x2+A3)@Wfc_top + G@Wcomb + cntm⊗bvec + bfc
    final_gemm<<<(N_NODES + 15) / 16, 256, 0, stream>>>(
        bufX, bufA, G, cntm, Wfc, Wcomb, bvec, bfc, (float*)d_out, N_NODES);
}

// Round 2
// 910.670 us; speedup vs baseline: 5.7032x; 5.7032x over previous
//
#include <hip/hip_runtime.h>

#define N_NODES 50000
#define N_EDGES 800000
#define NODE_DIM 128
#define EDGE_DIM 64
#define HIDDEN 128
#define OUT_DIM 64

// ---------------------------------------------------------------------------
// Histogram: cnt[col[e]]++ for node CSR; cntm[col[mcol[j]]]++ for meta CSR.
// ---------------------------------------------------------------------------
__global__ __launch_bounds__(256) void build_hist(
    const int* __restrict__ col, const int* __restrict__ mcol,
    int* __restrict__ cnt, int* __restrict__ cntm)
{
    int idx = blockIdx.x * 256 + threadIdx.x;
    if (idx < N_EDGES) {
        atomicAdd(&cnt[col[idx]], 1);
    } else if (idx < 2 * N_EDGES) {
        int j = idx - N_EDGES;
        int d = col[mcol[j]];
        atomicAdd(&cntm[d], 1);
    }
}

// ---------------------------------------------------------------------------
// Exclusive scan over 50000 counters (two arrays, one block each).
// Writes off[0..N] and a mutable cursor copy pos[0..N-1].
// ---------------------------------------------------------------------------
__global__ __launch_bounds__(1024) void scan50k(
    const int* __restrict__ cnt, int* __restrict__ off, int* __restrict__ pos,
    const int* __restrict__ cntm, int* __restrict__ offm, int* __restrict__ posm)
{
    const int* c = (blockIdx.x == 0) ? cnt : cntm;
    int* o = (blockIdx.x == 0) ? off : offm;
    int* p = (blockIdx.x == 0) ? pos : posm;
    __shared__ int s[1024];
    __shared__ int carry;
    if (threadIdx.x == 0) carry = 0;
    __syncthreads();
    for (int base = 0; base < N_NODES; base += 1024) {
        int i = base + threadIdx.x;
        int v = (i < N_NODES) ? c[i] : 0;
        s[threadIdx.x] = v;
        __syncthreads();
        for (int d = 1; d < 1024; d <<= 1) {
            int t = (threadIdx.x >= (unsigned)d) ? s[threadIdx.x - d] : 0;
            __syncthreads();
            s[threadIdx.x] += t;
            __syncthreads();
        }
        int excl = carry + s[threadIdx.x] - v;
        if (i < N_NODES) { o[i] = excl; p[i] = excl; }
        __syncthreads();
        if (threadIdx.x == 1023) carry += s[1023];
        __syncthreads();
    }
    if (threadIdx.x == 0) o[N_NODES] = carry;
}

// ---------------------------------------------------------------------------
// Fill CSR payload arrays: src_ids bucketed by col[e]; srcm_ids by col[mcol].
// ---------------------------------------------------------------------------
__global__ __launch_bounds__(256) void fill_csr(
    const int* __restrict__ row, const int* __restrict__ col,
    const int* __restrict__ mrow, const int* __restrict__ mcol,
    int* __restrict__ pos, int* __restrict__ posm,
    int* __restrict__ src_ids, int* __restrict__ srcm_ids)
{
    int idx = blockIdx.x * 256 + threadIdx.x;
    if (idx < N_EDGES) {
        int c = col[idx];
        int p = atomicAdd(&pos[c], 1);
        src_ids[p] = row[idx];
    } else if (idx < 2 * N_EDGES) {
        int j = idx - N_EDGES;
        int d = col[mcol[j]];
        int p = atomicAdd(&posm[d], 1);
        srcm_ids[p] = mrow[j];
    }
}

// ---------------------------------------------------------------------------
// acc[n] = sum over CSR bucket n of feat[src] (128 floats). One wave/node:
// 32 lanes = one row (float4 each), 2 edges in flight, shfl-combine halves.
// ---------------------------------------------------------------------------
__global__ __launch_bounds__(256) void gather_node(
    const float* __restrict__ feat, const int* __restrict__ off,
    const int* __restrict__ ids, float* __restrict__ acc)
{
    int w = blockIdx.x * 4 + (threadIdx.x >> 6);
    if (w >= N_NODES) return;
    int lane = threadIdx.x & 63;
    int half = lane >> 5;
    int l = lane & 31;
    int beg = off[w], end = off[w + 1];
    float4 s = make_float4(0.f, 0.f, 0.f, 0.f);
    for (int i = beg + half; i < end; i += 2) {
        int src = ids[i];
        float4 v = ((const float4*)(feat + (size_t)src * 128))[l];
        s.x += v.x; s.y += v.y; s.z += v.z; s.w += v.w;
    }
    s.x += __shfl_xor(s.x, 32, 64);
    s.y += __shfl_xor(s.y, 32, 64);
    s.z += __shfl_xor(s.z, 32, 64);
    s.w += __shfl_xor(s.w, 32, 64);
    if (half == 0)
        ((float4*)(acc + (size_t)w * 128))[l] = s;
}

// ---------------------------------------------------------------------------
// G[n] = sum over meta bucket n of ef[src] (64 floats). 16 lanes/row,
// 4 edges in flight, two shfl-combine rounds.
// ---------------------------------------------------------------------------
__global__ __launch_bounds__(256) void gather_edge(
    const float* __restrict__ ef, const int* __restrict__ offm,
    const int* __restrict__ ids, float* __restrict__ G)
{
    int w = blockIdx.x * 4 + (threadIdx.x >> 6);
    if (w >= N_NODES) return;
    int lane = threadIdx.x & 63;
    int q = lane >> 4;
    int l = lane & 15;
    int beg = offm[w], end = offm[w + 1];
    float4 s = make_float4(0.f, 0.f, 0.f, 0.f);
    for (int i = beg + q; i < end; i += 4) {
        int src = ids[i];
        float4 v = ((const float4*)(ef + (size_t)src * 64))[l];
        s.x += v.x; s.y += v.y; s.z += v.z; s.w += v.w;
    }
    s.x += __shfl_xor(s.x, 32, 64);
    s.y += __shfl_xor(s.y, 32, 64);
    s.z += __shfl_xor(s.z, 32, 64);
    s.w += __shfl_xor(s.w, 32, 64);
    s.x += __shfl_xor(s.x, 16, 64);
    s.y += __shfl_xor(s.y, 16, 64);
    s.z += __shfl_xor(s.z, 16, 64);
    s.w += __shfl_xor(s.w, 16, 64);
    if (q == 0)
        ((float4*)(G + (size_t)w * 64))[l] = s;
}

// ---------------------------------------------------------------------------
// X = relu(A @ W + deg⊗bias), deg[r] = off[r+1]-off[r].
// ---------------------------------------------------------------------------
__global__ __launch_bounds__(256) void gemm128_relu(
    const float* __restrict__ A, const float* __restrict__ W,
    const float* __restrict__ bias, const int* __restrict__ off,
    float* __restrict__ X, int M)
{
    __shared__ float Ws[64 * 128];   // 32 KB
    __shared__ float As[8][128];     // 4 KB
    int r0 = blockIdx.x * 8;
    for (int i = threadIdx.x; i < 8 * 32; i += 256) {
        int rr = i >> 5, cc = i & 31;
        int gr = r0 + rr;
        float4 v = make_float4(0.f, 0.f, 0.f, 0.f);
        if (gr < M) v = ((const float4*)(A + (size_t)gr * 128))[cc];
        ((float4*)(&As[rr][0]))[cc] = v;
    }
    float acc0 = 0.f, acc1 = 0.f, acc2 = 0.f, acc3 = 0.f;
    int rl = threadIdx.x >> 5;
    int cg = threadIdx.x & 31;
    for (int kb = 0; kb < 2; kb++) {
        __syncthreads();
        for (int i = threadIdx.x; i < 64 * 32; i += 256)
            ((float4*)Ws)[i] = ((const float4*)(W + kb * 64 * 128))[i];
        __syncthreads();
        #pragma unroll 8
        for (int k = 0; k < 64; k++) {
            float a = As[rl][kb * 64 + k];
            float4 w = *(const float4*)(&Ws[k * 128 + cg * 4]);
            acc0 = fmaf(a, w.x, acc0);
            acc1 = fmaf(a, w.y, acc1);
            acc2 = fmaf(a, w.z, acc2);
            acc3 = fmaf(a, w.w, acc3);
        }
    }
    int r = r0 + rl;
    if (r < M) {
        float dg = (float)(off[r + 1] - off[r]);
        float4 bb = ((const float4*)bias)[cg];
        float4 o;
        o.x = fmaxf(fmaf(dg, bb.x, acc0), 0.0f);
        o.y = fmaxf(fmaf(dg, bb.y, acc1), 0.0f);
        o.z = fmaxf(fmaf(dg, bb.z, acc2), 0.0f);
        o.w = fmaxf(fmaf(dg, bb.w, acc3), 0.0f);
        ((float4*)(X + (size_t)r * 128))[cg] = o;
    }
}

// ---------------------------------------------------------------------------
// Wcomb = We @ Wfc[128:256], bvec = be @ Wfc[128:256]
// ---------------------------------------------------------------------------
__global__ __launch_bounds__(256) void precompute_wcomb(
    const float* __restrict__ We, const float* __restrict__ be,
    const float* __restrict__ Wfc, float* __restrict__ Wcomb,
    float* __restrict__ bvec)
{
    int idx = blockIdx.x * 256 + threadIdx.x;
    if (idx < 64 * 64) {
        int k = idx >> 6, c = idx & 63;
        float s = 0.f;
        for (int h = 0; h < 128; h++)
            s = fmaf(We[k * 128 + h], Wfc[(128 + h) * 64 + c], s);
        Wcomb[idx] = s;
    } else if (idx < 64 * 64 + 64) {
        int c = idx - 64 * 64;
        float s = 0.f;
        for (int h = 0; h < 128; h++)
            s = fmaf(be[h], Wfc[(128 + h) * 64 + c], s);
        bvec[c] = s;
    }
}

// ---------------------------------------------------------------------------
// out = (X2 + A3) @ Wfc[0:128] + G @ Wcomb + cntm⊗bvec + bfc
// cntm[r] = offm[r+1]-offm[r].
// ---------------------------------------------------------------------------
__global__ __launch_bounds__(256) void final_gemm(
    const float* __restrict__ X2, const float* __restrict__ A3,
    const float* __restrict__ G, const int* __restrict__ offm,
    const float* __restrict__ Wfc, const float* __restrict__ Wcomb,
    const float* __restrict__ bvec, const float* __restrict__ bfc,
    float* __restrict__ out, int M)
{
    __shared__ float Wt[128 * 64];
    __shared__ float Wc[64 * 64];
    __shared__ float Ss[16][128];
    __shared__ float Gs[16][64];
    int r0 = blockIdx.x * 16;
    for (int i = threadIdx.x; i < 128 * 16; i += 256)
        ((float4*)Wt)[i] = ((const float4*)Wfc)[i];
    for (int i = threadIdx.x; i < 64 * 16; i += 256)
        ((float4*)Wc)[i] = ((const float4*)Wcomb)[i];
    for (int i = threadIdx.x; i < 16 * 32; i += 256) {
        int rr = i >> 5, cc = i & 31;
        int gr = r0 + rr;
        float4 v = make_float4(0.f, 0.f, 0.f, 0.f);
        if (gr < M) {
            float4 a = ((const float4*)(X2 + (size_t)gr * 128))[cc];
            float4 b = ((const float4*)(A3 + (size_t)gr * 128))[cc];
            v = make_float4(a.x + b.x, a.y + b.y, a.z + b.z, a.w + b.w);
        }
        ((float4*)(&Ss[rr][0]))[cc] = v;
    }
    for (int i = threadIdx.x; i < 16 * 16; i += 256) {
        int rr = i >> 4, cc = i & 15;
        int gr = r0 + rr;
        float4 v = make_float4(0.f, 0.f, 0.f, 0.f);
        if (gr < M) v = ((const float4*)(G + (size_t)gr * 64))[cc];
        ((float4*)(&Gs[rr][0]))[cc] = v;
    }
    __syncthreads();
    int rl = threadIdx.x >> 4;
    int cg = threadIdx.x & 15;
    int r = r0 + rl;
    float cnt = (r < M) ? (float)(offm[r + 1] - offm[r]) : 0.0f;
    float4 bv = ((const float4*)bvec)[cg];
    float4 bf = ((const float4*)bfc)[cg];
    float a0 = fmaf(cnt, bv.x, bf.x);
    float a1 = fmaf(cnt, bv.y, bf.y);
    float a2 = fmaf(cnt, bv.z, bf.z);
    float a3 = fmaf(cnt, bv.w, bf.w);
    #pragma unroll 4
    for (int k = 0; k < 128; k++) {
        float a = Ss[rl][k];
        float4 w = *(const float4*)(&Wt[k * 64 + cg * 4]);
        a0 = fmaf(a, w.x, a0);
        a1 = fmaf(a, w.y, a1);
        a2 = fmaf(a, w.z, a2);
        a3 = fmaf(a, w.w, a3);
    }
    #pragma unroll 4
    for (int k = 0; k < 64; k++) {
        float g = Gs[rl][k];
        float4 w = *(const float4*)(&Wc[k * 64 + cg * 4]);
        a0 = fmaf(g, w.x, a0);
        a1 = fmaf(g, w.y, a1);
        a2 = fmaf(g, w.z, a2);
        a3 = fmaf(g, w.w, a3);
    }
    if (r < M)
        ((float4*)(out + (size_t)r * 64))[cg] = make_float4(a0, a1, a2, a3);
}

extern "C" void kernel_launch(void* const* d_in, const int* in_sizes, int n_in,
                              void* d_out, int out_size, void* d_ws, size_t ws_size,
                              hipStream_t stream)
{
    const float* nf  = (const float*)d_in[0];
    const int*   ei  = (const int*)d_in[1];
    const float* ef  = (const float*)d_in[2];
    const int*   emi = (const int*)d_in[3];
    const float* W1  = (const float*)d_in[4];
    const float* b1  = (const float*)d_in[5];
    const float* W2  = (const float*)d_in[6];
    const float* b2  = (const float*)d_in[7];
    const float* We  = (const float*)d_in[8];
    const float* be  = (const float*)d_in[9];
    const float* Wfc = (const float*)d_in[10];
    const float* bfc = (const float*)d_in[11];

    const int* row  = ei;
    const int* col  = ei + N_EDGES;
    const int* mrow = emi;
    const int* mcol = emi + N_EDGES;

    // workspace layout
    float* ws     = (float*)d_ws;
    float* bufA   = ws;                                   // 50000*128
    float* bufX   = bufA + (size_t)N_NODES * HIDDEN;      // 50000*128
    float* G      = bufX + (size_t)N_NODES * HIDDEN;      // 50000*64
    float* Wcomb  = G + (size_t)N_NODES * EDGE_DIM;       // 4096
    float* bvec   = Wcomb + 64 * 64;                      // 64
    int*   off    = (int*)(bvec + 64);                    // N+1
    int*   pos    = off + (N_NODES + 1);                  // N
    int*   offm   = pos + N_NODES;                        // N+1
    int*   posm   = offm + (N_NODES + 1);                 // N
    int*   cnt    = posm + N_NODES;                       // N   (contiguous w/ cntm)
    int*   cntm   = cnt + N_NODES;                        // N
    int*   src_ids  = cntm + N_NODES;                     // N_EDGES
    int*   srcm_ids = src_ids + N_EDGES;                  // N_EDGES

    // zero histogram counters only (cnt+cntm contiguous)
    hipMemsetAsync(cnt, 0, 2 * (size_t)N_NODES * sizeof(int), stream);

    precompute_wcomb<<<17, 256, 0, stream>>>(We, be, Wfc, Wcomb, bvec);

    // CSR build
    build_hist<<<(2 * N_EDGES + 255) / 256, 256, 0, stream>>>(col, mcol, cnt, cntm);
    scan50k<<<2, 1024, 0, stream>>>(cnt, off, pos, cntm, offm, posm);
    fill_csr<<<(2 * N_EDGES + 255) / 256, 256, 0, stream>>>(
        row, col, mrow, mcol, pos, posm, src_ids, srcm_ids);

    // layer 1: A1 = seg-sum(nf); x1 = relu(A1@W1 + deg b1)
    gather_node<<<(N_NODES + 3) / 4, 256, 0, stream>>>(nf, off, src_ids, bufA);
    gemm128_relu<<<(N_NODES + 7) / 8, 256, 0, stream>>>(bufA, W1, b1, off, bufX, N_NODES);

    // layer 2
    gather_node<<<(N_NODES + 3) / 4, 256, 0, stream>>>(bufX, off, src_ids, bufA);
    gemm128_relu<<<(N_NODES + 7) / 8, 256, 0, stream>>>(bufA, W2, b2, off, bufX, N_NODES);

    // agg_neighbors = seg-sum(x2)
    gather_node<<<(N_NODES + 3) / 4, 256, 0, stream>>>(bufX, off, src_ids, bufA);

    // edge path
    gather_edge<<<(N_NODES + 3) / 4, 256, 0, stream>>>(ef, offm, srcm_ids, G);

    // epilogue
    final_gemm<<<(N_NODES + 15) / 16, 256, 0, stream>>>(
        bufX, bufA, G, offm, Wfc, Wcomb, bvec, bfc, (float*)d_out, N_NODES);
}

// Round 3
// 851.196 us; speedup vs baseline: 6.1017x; 1.0699x over previous
//
#include <hip/hip_runtime.h>

#define N_NODES 50000
#define N_EDGES 800000
#define NODE_DIM 128
#define EDGE_DIM 64
#define HIDDEN 128
#define OUT_DIM 64
#define NCAT (2 * N_NODES)          // concatenated histogram length
#define SCAN_BLOCKS ((NCAT + 1023) / 1024)   // 98

// ---------------------------------------------------------------------------
// Histogram: cnt[col[e]]++ (node CSR); cntm[col[mcol[j]]]++ (meta CSR).
// cnt and cntm are contiguous: one 100K array for the scan.
// ---------------------------------------------------------------------------
__global__ __launch_bounds__(256) void build_hist(
    const int* __restrict__ col, const int* __restrict__ mcol,
    int* __restrict__ cnt, int* __restrict__ cntm)
{
    int idx = blockIdx.x * 256 + threadIdx.x;
    if (idx < N_EDGES) {
        atomicAdd(&cnt[col[idx]], 1);
    } else if (idx < 2 * N_EDGES) {
        int j = idx - N_EDGES;
        atomicAdd(&cntm[col[mcol[j]]], 1);
    }
}

// ---------------------------------------------------------------------------
// Decoupled scan over the concatenated 100K histogram.
// ---------------------------------------------------------------------------
__global__ __launch_bounds__(1024) void scan_partials(
    const int* __restrict__ H, int* __restrict__ P)
{
    int t = blockIdx.x * 1024 + threadIdx.x;
    int v = (t < NCAT) ? H[t] : 0;
    for (int d = 1; d < 64; d <<= 1) v += __shfl_xor(v, d, 64);
    __shared__ int wsum[16];
    if ((threadIdx.x & 63) == 0) wsum[threadIdx.x >> 6] = v;
    __syncthreads();
    if (threadIdx.x == 0) {
        int s = 0;
        for (int i = 0; i < 16; i++) s += wsum[i];
        P[blockIdx.x] = s;
    }
}

__global__ void scan_mid(const int* __restrict__ P, int* __restrict__ Pex,
                         int* __restrict__ off, int* __restrict__ offm)
{
    if (threadIdx.x == 0) {
        int run = 0;
        for (int b = 0; b < SCAN_BLOCKS; b++) { Pex[b] = run; run += P[b]; }
        off[N_NODES] = N_EDGES;   // totals are known constants
        offm[N_NODES] = N_EDGES;
    }
}

__global__ __launch_bounds__(1024) void scan_final(
    const int* __restrict__ H, const int* __restrict__ Pex,
    int* __restrict__ off, int* __restrict__ pos,
    int* __restrict__ offm, int* __restrict__ posm)
{
    int t = blockIdx.x * 1024 + threadIdx.x;
    int lane = threadIdx.x & 63, wid = threadIdx.x >> 6;
    int v = (t < NCAT) ? H[t] : 0;
    int x = v;
    for (int d = 1; d < 64; d <<= 1) {
        int u = __shfl_up(x, d, 64);
        if (lane >= d) x += u;
    }
    __shared__ int wsum[16];
    __shared__ int wex[16];
    if (lane == 63) wsum[wid] = x;
    __syncthreads();
    if (threadIdx.x == 0) {
        int run = 0;
        for (int i = 0; i < 16; i++) { wex[i] = run; run += wsum[i]; }
    }
    __syncthreads();
    int excl = Pex[blockIdx.x] + wex[wid] + x - v;
    if (t < N_NODES) {
        off[t] = excl; pos[t] = excl;
    } else if (t < NCAT) {
        int u = t - N_NODES;
        offm[u] = excl - N_EDGES; posm[u] = excl - N_EDGES;
    }
}

// ---------------------------------------------------------------------------
// Fill CSR payloads: src_ids bucketed by col[e]; srcm_ids by col[mcol[j]].
// ---------------------------------------------------------------------------
__global__ __launch_bounds__(256) void fill_csr(
    const int* __restrict__ row, const int* __restrict__ col,
    const int* __restrict__ mrow, const int* __restrict__ mcol,
    int* __restrict__ pos, int* __restrict__ posm,
    int* __restrict__ src_ids, int* __restrict__ srcm_ids)
{
    int idx = blockIdx.x * 256 + threadIdx.x;
    if (idx < N_EDGES) {
        int p = atomicAdd(&pos[col[idx]], 1);
        src_ids[p] = row[idx];
    } else if (idx < 2 * N_EDGES) {
        int j = idx - N_EDGES;
        int p = atomicAdd(&posm[col[mcol[j]]], 1);
        srcm_ids[p] = mrow[j];
    }
}

// ---------------------------------------------------------------------------
// Wcomb = We @ Wfc[128:256], bvec = be @ Wfc[128:256]
// ---------------------------------------------------------------------------
__global__ __launch_bounds__(256) void precompute_wcomb(
    const float* __restrict__ We, const float* __restrict__ be,
    const float* __restrict__ Wfc, float* __restrict__ Wcomb,
    float* __restrict__ bvec)
{
    int idx = blockIdx.x * 256 + threadIdx.x;
    if (idx < 64 * 64) {
        int k = idx >> 6, c = idx & 63;
        float s = 0.f;
        for (int h = 0; h < 128; h++)
            s = fmaf(We[k * 128 + h], Wfc[(128 + h) * 64 + c], s);
        Wcomb[idx] = s;
    } else if (idx < 64 * 64 + 64) {
        int c = idx - 64 * 64;
        float s = 0.f;
        for (int h = 0; h < 128; h++)
            s = fmaf(be[h], Wfc[(128 + h) * 64 + c], s);
        bvec[c] = s;
    }
}

// ---------------------------------------------------------------------------
// Fused gather + GEMM: X = relu(segsum(feat)@W + deg⊗bias).
// Block: 8 rows, 256 threads. Gather into LDS, then 128x128 GEMM from LDS.
// ---------------------------------------------------------------------------
__global__ __launch_bounds__(256) void gather_gemm_relu(
    const float* __restrict__ feat, const int* __restrict__ off,
    const int* __restrict__ ids, const float* __restrict__ W,
    const float* __restrict__ bias, float* __restrict__ X, int M)
{
    __shared__ float Ws[64 * 128];   // 32 KB
    __shared__ float As[8][128];     // 4 KB
    int r0 = blockIdx.x * 8;
    int wid = threadIdx.x >> 6;
    int lane = threadIdx.x & 63;
    int half = lane >> 5;
    int l = lane & 31;
    #pragma unroll
    for (int rr = wid * 2; rr < wid * 2 + 2; rr++) {
        int r = r0 + rr;
        float4 s = make_float4(0.f, 0.f, 0.f, 0.f);
        if (r < M) {
            int beg = off[r], end = off[r + 1];
            for (int i = beg + half; i < end; i += 2) {
                int src = ids[i];
                float4 v = ((const float4*)(feat + (size_t)src * 128))[l];
                s.x += v.x; s.y += v.y; s.z += v.z; s.w += v.w;
            }
        }
        s.x += __shfl_xor(s.x, 32, 64);
        s.y += __shfl_xor(s.y, 32, 64);
        s.z += __shfl_xor(s.z, 32, 64);
        s.w += __shfl_xor(s.w, 32, 64);
        if (half == 0) ((float4*)(&As[rr][0]))[l] = s;
    }
    float acc0 = 0.f, acc1 = 0.f, acc2 = 0.f, acc3 = 0.f;
    int rl = threadIdx.x >> 5;
    int cg = threadIdx.x & 31;
    for (int kb = 0; kb < 2; kb++) {
        __syncthreads();                // also covers As-ready on kb==0
        for (int i = threadIdx.x; i < 64 * 32; i += 256)
            ((float4*)Ws)[i] = ((const float4*)(W + kb * 64 * 128))[i];
        __syncthreads();
        #pragma unroll 8
        for (int k = 0; k < 64; k++) {
            float a = As[rl][kb * 64 + k];
            float4 w = *(const float4*)(&Ws[k * 128 + cg * 4]);
            acc0 = fmaf(a, w.x, acc0);
            acc1 = fmaf(a, w.y, acc1);
            acc2 = fmaf(a, w.z, acc2);
            acc3 = fmaf(a, w.w, acc3);
        }
    }
    int r = r0 + rl;
    if (r < M) {
        float dg = (float)(off[r + 1] - off[r]);
        float4 bb = ((const float4*)bias)[cg];
        float4 o;
        o.x = fmaxf(fmaf(dg, bb.x, acc0), 0.0f);
        o.y = fmaxf(fmaf(dg, bb.y, acc1), 0.0f);
        o.z = fmaxf(fmaf(dg, bb.z, acc2), 0.0f);
        o.w = fmaxf(fmaf(dg, bb.w, acc3), 0.0f);
        ((float4*)(X + (size_t)r * 128))[cg] = o;
    }
}

// ---------------------------------------------------------------------------
// Layer 2 fused further: x2 = relu(segsum(x1)@W2 + deg⊗b2); Z = x2 @ Wfc_top.
// Z is 64-wide so the final aggregation gathers half the bytes.
// ---------------------------------------------------------------------------
__global__ __launch_bounds__(256) void gather_gemm_relu_proj(
    const float* __restrict__ feat, const int* __restrict__ off,
    const int* __restrict__ ids, const float* __restrict__ W,
    const float* __restrict__ bias, const float* __restrict__ Wfc,
    float* __restrict__ Z, int M)
{
    __shared__ float Ws[64 * 128];   // 32 KB (reused for Wfc_top: 128x64)
    __shared__ float As[8][128];     // 4 KB  (reused for x2)
    int r0 = blockIdx.x * 8;
    int wid = threadIdx.x >> 6;
    int lane = threadIdx.x & 63;
    int half = lane >> 5;
    int l = lane & 31;
    #pragma unroll
    for (int rr = wid * 2; rr < wid * 2 + 2; rr++) {
        int r = r0 + rr;
        float4 s = make_float4(0.f, 0.f, 0.f, 0.f);
        if (r < M) {
            int beg = off[r], end = off[r + 1];
            for (int i = beg + half; i < end; i += 2) {
                int src = ids[i];
                float4 v = ((const float4*)(feat + (size_t)src * 128))[l];
                s.x += v.x; s.y += v.y; s.z += v.z; s.w += v.w;
            }
        }
        s.x += __shfl_xor(s.x, 32, 64);
        s.y += __shfl_xor(s.y, 32, 64);
        s.z += __shfl_xor(s.z, 32, 64);
        s.w += __shfl_xor(s.w, 32, 64);
        if (half == 0) ((float4*)(&As[rr][0]))[l] = s;
    }
    float acc0 = 0.f, acc1 = 0.f, acc2 = 0.f, acc3 = 0.f;
    int rl = threadIdx.x >> 5;
    int cg = threadIdx.x & 31;
    for (int kb = 0; kb < 2; kb++) {
        __syncthreads();
        for (int i = threadIdx.x; i < 64 * 32; i += 256)
            ((float4*)Ws)[i] = ((const float4*)(W + kb * 64 * 128))[i];
        __syncthreads();
        #pragma unroll 8
        for (int k = 0; k < 64; k++) {
            float a = As[rl][kb * 64 + k];
            float4 w = *(const float4*)(&Ws[k * 128 + cg * 4]);
            acc0 = fmaf(a, w.x, acc0);
            acc1 = fmaf(a, w.y, acc1);
            acc2 = fmaf(a, w.z, acc2);
            acc3 = fmaf(a, w.w, acc3);
        }
    }
    // x2 epilogue into As (reuse), Wfc_top into Ws (reuse)
    int r = r0 + rl;
    float dg = (r < M) ? (float)(off[r + 1] - off[r]) : 0.f;
    float4 bb = ((const float4*)bias)[cg];
    float4 o;
    o.x = fmaxf(fmaf(dg, bb.x, acc0), 0.0f);
    o.y = fmaxf(fmaf(dg, bb.y, acc1), 0.0f);
    o.z = fmaxf(fmaf(dg, bb.z, acc2), 0.0f);
    o.w = fmaxf(fmaf(dg, bb.w, acc3), 0.0f);
    __syncthreads();                 // all GEMM reads of As/Ws complete
    ((float4*)(&As[rl][0]))[cg] = o;
    for (int i = threadIdx.x; i < 128 * 16; i += 256)
        ((float4*)Ws)[i] = ((const float4*)Wfc)[i];   // top half: rows 0..127
    __syncthreads();
    // z = x2 @ Wfc_top : 8 rows x 64 cols; each thread 2 cols
    float z0 = 0.f, z1 = 0.f;
    #pragma unroll 8
    for (int k = 0; k < 128; k++) {
        float a = As[rl][k];
        float2 w = *(const float2*)(&Ws[k * 64 + cg * 2]);
        z0 = fmaf(a, w.x, z0);
        z1 = fmaf(a, w.y, z1);
    }
    if (r < M)
        ((float2*)(Z + (size_t)r * 64))[cg] = make_float2(z0, z1);
}

// ---------------------------------------------------------------------------
// Epilogue: out[n] = z[n] + segsum(z) + segsum_m(ef)@Wcomb + cntm⊗bvec + bfc.
// Block: 16 rows, 256 threads. Both gathers are 64-float rows.
// ---------------------------------------------------------------------------
__global__ __launch_bounds__(256) void epilogue(
    const float* __restrict__ Z, const float* __restrict__ ef,
    const int* __restrict__ off, const int* __restrict__ ids,
    const int* __restrict__ offm, const int* __restrict__ mids,
    const float* __restrict__ Wcomb, const float* __restrict__ bvec,
    const float* __restrict__ bfc, float* __restrict__ out, int M)
{
    __shared__ float Wc[64 * 64];    // 16 KB
    __shared__ float Ss[16][64];     // 4 KB : z + agg(z)
    __shared__ float Gs[16][64];     // 4 KB : agg(ef)
    int r0 = blockIdx.x * 16;
    for (int i = threadIdx.x; i < 1024; i += 256)
        ((float4*)Wc)[i] = ((const float4*)Wcomb)[i];
    int wid = threadIdx.x >> 6;
    int lane = threadIdx.x & 63;
    int q = lane >> 4;
    int l = lane & 15;
    #pragma unroll
    for (int rr = wid * 4; rr < wid * 4 + 4; rr++) {
        int r = r0 + rr;
        // agg(z) over node CSR
        float4 s = make_float4(0.f, 0.f, 0.f, 0.f);
        if (r < M) {
            int beg = off[r], end = off[r + 1];
            for (int i = beg + q; i < end; i += 4) {
                int src = ids[i];
                float4 v = ((const float4*)(Z + (size_t)src * 64))[l];
                s.x += v.x; s.y += v.y; s.z += v.z; s.w += v.w;
            }
        }
        s.x += __shfl_xor(s.x, 32, 64);
        s.y += __shfl_xor(s.y, 32, 64);
        s.z += __shfl_xor(s.z, 32, 64);
        s.w += __shfl_xor(s.w, 32, 64);
        s.x += __shfl_xor(s.x, 16, 64);
        s.y += __shfl_xor(s.y, 16, 64);
        s.z += __shfl_xor(s.z, 16, 64);
        s.w += __shfl_xor(s.w, 16, 64);
        if (q == 0 && r < M) {
            float4 zr = ((const float4*)(Z + (size_t)r * 64))[l];
            ((float4*)(&Ss[rr][0]))[l] =
                make_float4(zr.x + s.x, zr.y + s.y, zr.z + s.z, zr.w + s.w);
        }
        // agg(ef) over meta CSR
        float4 g = make_float4(0.f, 0.f, 0.f, 0.f);
        if (r < M) {
            int beg = offm[r], end = offm[r + 1];
            for (int i = beg + q; i < end; i += 4) {
                int src = mids[i];
                float4 v = ((const float4*)(ef + (size_t)src * 64))[l];
                g.x += v.x; g.y += v.y; g.z += v.z; g.w += v.w;
            }
        }
        g.x += __shfl_xor(g.x, 32, 64);
        g.y += __shfl_xor(g.y, 32, 64);
        g.z += __shfl_xor(g.z, 32, 64);
        g.w += __shfl_xor(g.w, 32, 64);
        g.x += __shfl_xor(g.x, 16, 64);
        g.y += __shfl_xor(g.y, 16, 64);
        g.z += __shfl_xor(g.z, 16, 64);
        g.w += __shfl_xor(g.w, 16, 64);
        if (q == 0 && r < M) ((float4*)(&Gs[rr][0]))[l] = g;
    }
    __syncthreads();
    int rl = threadIdx.x >> 4;
    int cg = threadIdx.x & 15;
    int r = r0 + rl;
    if (r >= M) return;
    float cnt = (float)(offm[r + 1] - offm[r]);
    float4 bv = ((const float4*)bvec)[cg];
    float4 bf = ((const float4*)bfc)[cg];
    float4 sq = *(const float4*)(&Ss[rl][cg * 4]);
    float a0 = sq.x + fmaf(cnt, bv.x, bf.x);
    float a1 = sq.y + fmaf(cnt, bv.y, bf.y);
    float a2 = sq.z + fmaf(cnt, bv.z, bf.z);
    float a3 = sq.w + fmaf(cnt, bv.w, bf.w);
    #pragma unroll 4
    for (int k = 0; k < 64; k++) {
        float g = Gs[rl][k];
        float4 w = *(const float4*)(&Wc[k * 64 + cg * 4]);
        a0 = fmaf(g, w.x, a0);
        a1 = fmaf(g, w.y, a1);
        a2 = fmaf(g, w.z, a2);
        a3 = fmaf(g, w.w, a3);
    }
    ((float4*)(out + (size_t)r * 64))[cg] = make_float4(a0, a1, a2, a3);
}

extern "C" void kernel_launch(void* const* d_in, const int* in_sizes, int n_in,
                              void* d_out, int out_size, void* d_ws, size_t ws_size,
                              hipStream_t stream)
{
    const float* nf  = (const float*)d_in[0];
    const int*   ei  = (const int*)d_in[1];
    const float* ef  = (const float*)d_in[2];
    const int*   emi = (const int*)d_in[3];
    const float* W1  = (const float*)d_in[4];
    const float* b1  = (const float*)d_in[5];
    const float* W2  = (const float*)d_in[6];
    const float* b2  = (const float*)d_in[7];
    const float* We  = (const float*)d_in[8];
    const float* be  = (const float*)d_in[9];
    const float* Wfc = (const float*)d_in[10];
    const float* bfc = (const float*)d_in[11];

    const int* row  = ei;
    const int* col  = ei + N_EDGES;
    const int* mrow = emi;
    const int* mcol = emi + N_EDGES;

    // workspace layout
    float* ws    = (float*)d_ws;
    float* bufX  = ws;                                    // 50000*128 (x1)
    float* Z     = bufX + (size_t)N_NODES * HIDDEN;       // 50000*64
    float* Wcomb = Z + (size_t)N_NODES * OUT_DIM;         // 4096
    float* bvec  = Wcomb + 64 * 64;                       // 64
    int*   off   = (int*)(bvec + 64);                     // N+1
    int*   pos   = off + (N_NODES + 1);                   // N
    int*   offm  = pos + N_NODES;                         // N+1
    int*   posm  = offm + (N_NODES + 1);                  // N
    int*   cnt   = posm + N_NODES;                        // N  } contiguous 100K
    int*   cntm  = cnt + N_NODES;                         // N  } for the scan
    int*   P     = cntm + N_NODES;                        // SCAN_BLOCKS
    int*   Pex   = P + SCAN_BLOCKS;                       // SCAN_BLOCKS
    int*   src_ids  = Pex + SCAN_BLOCKS;                  // N_EDGES
    int*   srcm_ids = src_ids + N_EDGES;                  // N_EDGES

    hipMemsetAsync(cnt, 0, 2 * (size_t)N_NODES * sizeof(int), stream);

    precompute_wcomb<<<17, 256, 0, stream>>>(We, be, Wfc, Wcomb, bvec);

    // CSR build (node + meta share one histogram/scan pipeline)
    build_hist<<<(2 * N_EDGES + 255) / 256, 256, 0, stream>>>(col, mcol, cnt, cntm);
    scan_partials<<<SCAN_BLOCKS, 1024, 0, stream>>>(cnt, P);
    scan_mid<<<1, 64, 0, stream>>>(P, Pex, off, offm);
    scan_final<<<SCAN_BLOCKS, 1024, 0, stream>>>(cnt, Pex, off, pos, offm, posm);
    fill_csr<<<(2 * N_EDGES + 255) / 256, 256, 0, stream>>>(
        row, col, mrow, mcol, pos, posm, src_ids, srcm_ids);

    // layer 1: x1 = relu(segsum(nf)@W1 + deg b1)
    gather_gemm_relu<<<(N_NODES + 7) / 8, 256, 0, stream>>>(
        nf, off, src_ids, W1, b1, bufX, N_NODES);

    // layer 2 + projection: z = relu(segsum(x1)@W2 + deg b2) @ Wfc_top
    gather_gemm_relu_proj<<<(N_NODES + 7) / 8, 256, 0, stream>>>(
        bufX, off, src_ids, W2, b2, Wfc, Z, N_NODES);

    // epilogue: out = z + agg(z) + agg_m(ef)@Wcomb + cntm bvec + bfc
    epilogue<<<(N_NODES + 15) / 16, 256, 0, stream>>>(
        Z, ef, off, src_ids, offm, srcm_ids, Wcomb, bvec, bfc,
        (float*)d_out, N_NODES);
}

// Round 5
// 761.138 us; speedup vs baseline: 6.8237x; 1.1183x over previous
//
#include <hip/hip_runtime.h>

#define N_NODES 50000
#define N_EDGES 800000
#define NODE_DIM 128
#define EDGE_DIM 64
#define HIDDEN 128
#define OUT_DIM 64
#define NCAT (2 * N_NODES)
#define SCAN_BLOCKS ((NCAT + 1023) / 1024)   // 98

typedef unsigned short u16;
typedef unsigned int u32;

__device__ __forceinline__ float bflo(u32 u) { return __builtin_bit_cast(float, u << 16); }
__device__ __forceinline__ float bfhi(u32 u) { return __builtin_bit_cast(float, u & 0xFFFF0000u); }
__device__ __forceinline__ u32 pack2(float x, float y) {
    u32 a = __builtin_bit_cast(u32, x);
    a += 0x7FFFu + ((a >> 16) & 1u);
    u32 b = __builtin_bit_cast(u32, y);
    b += 0x7FFFu + ((b >> 16) & 1u);
    return (a >> 16) | (b & 0xFFFF0000u);
}

// ---------------------------------------------------------------------------
// CSR build: histogram, decoupled scan, fill.
// ---------------------------------------------------------------------------
__global__ __launch_bounds__(256) void build_hist(
    const int* __restrict__ col, const int* __restrict__ mcol,
    int* __restrict__ cnt, int* __restrict__ cntm)
{
    int idx = blockIdx.x * 256 + threadIdx.x;
    if (idx < N_EDGES) {
        atomicAdd(&cnt[col[idx]], 1);
    } else if (idx < 2 * N_EDGES) {
        int j = idx - N_EDGES;
        atomicAdd(&cntm[col[mcol[j]]], 1);
    }
}

__global__ __launch_bounds__(1024) void scan_partials(
    const int* __restrict__ H, int* __restrict__ P)
{
    int t = blockIdx.x * 1024 + threadIdx.x;
    int v = (t < NCAT) ? H[t] : 0;
    for (int d = 1; d < 64; d <<= 1) v += __shfl_xor(v, d, 64);
    __shared__ int wsum[16];
    if ((threadIdx.x & 63) == 0) wsum[threadIdx.x >> 6] = v;
    __syncthreads();
    if (threadIdx.x == 0) {
        int s = 0;
        for (int i = 0; i < 16; i++) s += wsum[i];
        P[blockIdx.x] = s;
    }
}

__global__ void scan_mid(const int* __restrict__ P, int* __restrict__ Pex,
                         int* __restrict__ off, int* __restrict__ offm)
{
    if (threadIdx.x == 0) {
        int run = 0;
        for (int b = 0; b < SCAN_BLOCKS; b++) { Pex[b] = run; run += P[b]; }
        off[N_NODES] = N_EDGES;
        offm[N_NODES] = N_EDGES;
    }
}

__global__ __launch_bounds__(1024) void scan_final(
    const int* __restrict__ H, const int* __restrict__ Pex,
    int* __restrict__ off, int* __restrict__ pos,
    int* __restrict__ offm, int* __restrict__ posm)
{
    int t = blockIdx.x * 1024 + threadIdx.x;
    int lane = threadIdx.x & 63, wid = threadIdx.x >> 6;
    int v = (t < NCAT) ? H[t] : 0;
    int x = v;
    for (int d = 1; d < 64; d <<= 1) {
        int u = __shfl_up(x, d, 64);
        if (lane >= d) x += u;
    }
    __shared__ int wsum[16];
    __shared__ int wex[16];
    if (lane == 63) wsum[wid] = x;
    __syncthreads();
    if (threadIdx.x == 0) {
        int run = 0;
        for (int i = 0; i < 16; i++) { wex[i] = run; run += wsum[i]; }
    }
    __syncthreads();
    int excl = Pex[blockIdx.x] + wex[wid] + x - v;
    if (t < N_NODES) {
        off[t] = excl; pos[t] = excl;
    } else if (t < NCAT) {
        int u = t - N_NODES;
        offm[u] = excl - N_EDGES; posm[u] = excl - N_EDGES;
    }
}

__global__ __launch_bounds__(256) void fill_csr(
    const int* __restrict__ row, const int* __restrict__ col,
    const int* __restrict__ mrow, const int* __restrict__ mcol,
    int* __restrict__ pos, int* __restrict__ posm,
    int* __restrict__ src_ids, int* __restrict__ srcm_ids)
{
    int idx = blockIdx.x * 256 + threadIdx.x;
    if (idx < N_EDGES) {
        int p = atomicAdd(&pos[col[idx]], 1);
        src_ids[p] = row[idx];
    } else if (idx < 2 * N_EDGES) {
        int j = idx - N_EDGES;
        int p = atomicAdd(&posm[col[mcol[j]]], 1);
        srcm_ids[p] = mrow[j];
    }
}

// ---------------------------------------------------------------------------
// Wcomb = We @ Wfc[128:256], bvec = be @ Wfc[128:256]
// ---------------------------------------------------------------------------
__global__ __launch_bounds__(256) void precompute_wcomb(
    const float* __restrict__ We, const float* __restrict__ be,
    const float* __restrict__ Wfc, float* __restrict__ Wcomb,
    float* __restrict__ bvec)
{
    int idx = blockIdx.x * 256 + threadIdx.x;
    if (idx < 64 * 64) {
        int k = idx >> 6, c = idx & 63;
        float s = 0.f;
        for (int h = 0; h < 128; h++)
            s = fmaf(We[k * 128 + h], Wfc[(128 + h) * 64 + c], s);
        Wcomb[idx] = s;
    } else if (idx < 64 * 64 + 64) {
        int c = idx - 64 * 64;
        float s = 0.f;
        for (int h = 0; h < 128; h++)
            s = fmaf(be[h], Wfc[(128 + h) * 64 + c], s);
        bvec[c] = s;
    }
}

// ---------------------------------------------------------------------------
// Streaming GEMM: P = A(f32, Mx128) @ W(128x128) -> bf16. No bias.
// ---------------------------------------------------------------------------
__global__ __launch_bounds__(256) void gemm_f32_bf16(
    const float* __restrict__ A, const float* __restrict__ W,
    u16* __restrict__ P, int M)
{
    __shared__ float Ws[64 * 128];
    __shared__ float As[8][128];
    int r0 = blockIdx.x * 8;
    for (int i = threadIdx.x; i < 8 * 32; i += 256) {
        int rr = i >> 5, cc = i & 31;
        int gr = r0 + rr;
        float4 v = make_float4(0.f, 0.f, 0.f, 0.f);
        if (gr < M) v = ((const float4*)(A + (size_t)gr * 128))[cc];
        ((float4*)(&As[rr][0]))[cc] = v;
    }
    float a0 = 0.f, a1 = 0.f, a2 = 0.f, a3 = 0.f;
    int rl = threadIdx.x >> 5;
    int cg = threadIdx.x & 31;
    for (int kb = 0; kb < 2; kb++) {
        __syncthreads();
        for (int i = threadIdx.x; i < 64 * 32; i += 256)
            ((float4*)Ws)[i] = ((const float4*)(W + kb * 64 * 128))[i];
        __syncthreads();
        #pragma unroll 8
        for (int k = 0; k < 64; k++) {
            float a = As[rl][kb * 64 + k];
            float4 w = *(const float4*)(&Ws[k * 128 + cg * 4]);
            a0 = fmaf(a, w.x, a0); a1 = fmaf(a, w.y, a1);
            a2 = fmaf(a, w.z, a2); a3 = fmaf(a, w.w, a3);
        }
    }
    int r = r0 + rl;
    if (r < M) {
        uint2 o; o.x = pack2(a0, a1); o.y = pack2(a2, a3);
        ((uint2*)(P + (size_t)r * 128))[cg] = o;
    }
}

// ---------------------------------------------------------------------------
// Streaming GEMM: P = A(bf16, Mx128) @ W(128x128) -> bf16.
// ---------------------------------------------------------------------------
__global__ __launch_bounds__(256) void gemm_bf16_bf16(
    const u16* __restrict__ A, const float* __restrict__ W,
    u16* __restrict__ P, int M)
{
    __shared__ float Ws[64 * 128];
    __shared__ float As[8][128];
    {
        int rr = threadIdx.x >> 5, uu = threadIdx.x & 31;   // 256 = 8 rows x 32 uint2
        int gr = blockIdx.x * 8 + rr;
        uint2 u = make_uint2(0u, 0u);
        if (gr < M) u = ((const uint2*)(A + (size_t)gr * 128))[uu];
        As[rr][uu * 4 + 0] = bflo(u.x);
        As[rr][uu * 4 + 1] = bfhi(u.x);
        As[rr][uu * 4 + 2] = bflo(u.y);
        As[rr][uu * 4 + 3] = bfhi(u.y);
    }
    float a0 = 0.f, a1 = 0.f, a2 = 0.f, a3 = 0.f;
    int rl = threadIdx.x >> 5;
    int cg = threadIdx.x & 31;
    for (int kb = 0; kb < 2; kb++) {
        __syncthreads();
        for (int i = threadIdx.x; i < 64 * 32; i += 256)
            ((float4*)Ws)[i] = ((const float4*)(W + kb * 64 * 128))[i];
        __syncthreads();
        #pragma unroll 8
        for (int k = 0; k < 64; k++) {
            float a = As[rl][kb * 64 + k];
            float4 w = *(const float4*)(&Ws[k * 128 + cg * 4]);
            a0 = fmaf(a, w.x, a0); a1 = fmaf(a, w.y, a1);
            a2 = fmaf(a, w.z, a2); a3 = fmaf(a, w.w, a3);
        }
    }
    int r = blockIdx.x * 8 + rl;
    if (r < M) {
        uint2 o; o.x = pack2(a0, a1); o.y = pack2(a2, a3);
        ((uint2*)(P + (size_t)r * 128))[cg] = o;
    }
}

// ---------------------------------------------------------------------------
// X[w] = relu(segsum(P) + deg*bias). Pure gather, LDS-free. 1 row/wave.
// 32 lanes x uint2 (4 bf16) per edge; halves = 2 edges in flight; unroll x4.
// ---------------------------------------------------------------------------
__global__ __launch_bounds__(256) void agg_relu_bf16(
    const u16* __restrict__ P, const int* __restrict__ off,
    const int* __restrict__ ids, const float* __restrict__ bias,
    u16* __restrict__ X, int M)
{
    int w = blockIdx.x * 4 + (threadIdx.x >> 6);
    if (w >= M) return;
    int lane = threadIdx.x & 63;
    int half = lane >> 5;
    int l = lane & 31;
    int beg = off[w], end = off[w + 1];
    const uint2* F = (const uint2*)P;
    float a0 = 0.f, a1 = 0.f, a2 = 0.f, a3 = 0.f;
    int i = beg + half;
    for (; i + 6 < end; i += 8) {
        int s0 = ids[i], s1 = ids[i + 2], s2 = ids[i + 4], s3 = ids[i + 6];
        uint2 v0 = F[(size_t)s0 * 32 + l];
        uint2 v1 = F[(size_t)s1 * 32 + l];
        uint2 v2 = F[(size_t)s2 * 32 + l];
        uint2 v3 = F[(size_t)s3 * 32 + l];
        a0 += bflo(v0.x) + bflo(v1.x) + bflo(v2.x) + bflo(v3.x);
        a1 += bfhi(v0.x) + bfhi(v1.x) + bfhi(v2.x) + bfhi(v3.x);
        a2 += bflo(v0.y) + bflo(v1.y) + bflo(v2.y) + bflo(v3.y);
        a3 += bfhi(v0.y) + bfhi(v1.y) + bfhi(v2.y) + bfhi(v3.y);
    }
    for (; i < end; i += 2) {
        uint2 v = F[(size_t)ids[i] * 32 + l];
        a0 += bflo(v.x); a1 += bfhi(v.x); a2 += bflo(v.y); a3 += bfhi(v.y);
    }
    a0 += __shfl_xor(a0, 32, 64);
    a1 += __shfl_xor(a1, 32, 64);
    a2 += __shfl_xor(a2, 32, 64);
    a3 += __shfl_xor(a3, 32, 64);
    if (half == 0) {
        float dg = (float)(end - beg);
        float4 b = ((const float4*)bias)[l];
        a0 = fmaxf(fmaf(dg, b.x, a0), 0.f);
        a1 = fmaxf(fmaf(dg, b.y, a1), 0.f);
        a2 = fmaxf(fmaf(dg, b.z, a2), 0.f);
        a3 = fmaxf(fmaf(dg, b.w, a3), 0.f);
        uint2 o; o.x = pack2(a0, a1); o.y = pack2(a2, a3);
        ((uint2*)(X + (size_t)w * 128))[l] = o;
    }
}

// ---------------------------------------------------------------------------
// Epilogue aggregation (LDS-free): S[w] = x2[w] + segsum(x2)  (bf16),
// Gg[w] = segsum_m(ef) (bf16). 1 row/wave.
// ---------------------------------------------------------------------------
__global__ __launch_bounds__(256) void agg_epilogue(
    const u16* __restrict__ X2, const float* __restrict__ ef,
    const int* __restrict__ off, const int* __restrict__ ids,
    const int* __restrict__ offm, const int* __restrict__ mids,
    u16* __restrict__ S, u16* __restrict__ Gg, int M)
{
    int w = blockIdx.x * 4 + (threadIdx.x >> 6);
    if (w >= M) return;
    int lane = threadIdx.x & 63;
    int half = lane >> 5;
    int l = lane & 31;
    // ---- node gather over X2 (128 bf16 rows) ----
    {
        int beg = off[w], end = off[w + 1];
        const uint2* F = (const uint2*)X2;
        float a0 = 0.f, a1 = 0.f, a2 = 0.f, a3 = 0.f;
        int i = beg + half;
        for (; i + 6 < end; i += 8) {
            int s0 = ids[i], s1 = ids[i + 2], s2 = ids[i + 4], s3 = ids[i + 6];
            uint2 v0 = F[(size_t)s0 * 32 + l];
            uint2 v1 = F[(size_t)s1 * 32 + l];
            uint2 v2 = F[(size_t)s2 * 32 + l];
            uint2 v3 = F[(size_t)s3 * 32 + l];
            a0 += bflo(v0.x) + bflo(v1.x) + bflo(v2.x) + bflo(v3.x);
            a1 += bfhi(v0.x) + bfhi(v1.x) + bfhi(v2.x) + bfhi(v3.x);
            a2 += bflo(v0.y) + bflo(v1.y) + bflo(v2.y) + bflo(v3.y);
            a3 += bfhi(v0.y) + bfhi(v1.y) + bfhi(v2.y) + bfhi(v3.y);
        }
        for (; i < end; i += 2) {
            uint2 v = F[(size_t)ids[i] * 32 + l];
            a0 += bflo(v.x); a1 += bfhi(v.x); a2 += bflo(v.y); a3 += bfhi(v.y);
        }
        a0 += __shfl_xor(a0, 32, 64);
        a1 += __shfl_xor(a1, 32, 64);
        a2 += __shfl_xor(a2, 32, 64);
        a3 += __shfl_xor(a3, 32, 64);
        if (half == 0) {
            uint2 own = F[(size_t)w * 32 + l];
            a0 += bflo(own.x); a1 += bfhi(own.x);
            a2 += bflo(own.y); a3 += bfhi(own.y);
            uint2 o; o.x = pack2(a0, a1); o.y = pack2(a2, a3);
            ((uint2*)(S + (size_t)w * 128))[l] = o;
        }
    }
    // ---- meta gather over ef (64 f32 rows) ----
    {
        int beg = offm[w], end = offm[w + 1];
        const float2* E = (const float2*)ef;
        float g0 = 0.f, g1 = 0.f;
        int i = beg + half;
        for (; i + 6 < end; i += 8) {
            int s0 = mids[i], s1 = mids[i + 2], s2 = mids[i + 4], s3 = mids[i + 6];
            float2 v0 = E[(size_t)s0 * 32 + l];
            float2 v1 = E[(size_t)s1 * 32 + l];
            float2 v2 = E[(size_t)s2 * 32 + l];
            float2 v3 = E[(size_t)s3 * 32 + l];
            g0 += v0.x + v1.x + v2.x + v3.x;
            g1 += v0.y + v1.y + v2.y + v3.y;
        }
        for (; i < end; i += 2) {
            float2 v = E[(size_t)mids[i] * 32 + l];
            g0 += v.x; g1 += v.y;
        }
        g0 += __shfl_xor(g0, 32, 64);
        g1 += __shfl_xor(g1, 32, 64);
        if (half == 0)
            ((u32*)(Gg + (size_t)w * 64))[l] = pack2(g0, g1);
    }
}

// ---------------------------------------------------------------------------
// out = S@Wfc_top + Gg@Wcomb + cnt⊗bvec + bfc.  16 rows/block.
// ---------------------------------------------------------------------------
__global__ __launch_bounds__(256) void final_gemm(
    const u16* __restrict__ S, const u16* __restrict__ Gg,
    const int* __restrict__ offm, const float* __restrict__ Wfc,
    const float* __restrict__ Wcomb, const float* __restrict__ bvec,
    const float* __restrict__ bfc, float* __restrict__ out, int M)
{
    __shared__ float Wt[128 * 64];   // 32 KB
    __shared__ float Wc[64 * 64];    // 16 KB
    __shared__ float Ss[16][128];    // 8 KB
    __shared__ float Gs[16][64];     // 4 KB
    int r0 = blockIdx.x * 16;
    for (int i = threadIdx.x; i < 128 * 16; i += 256)
        ((float4*)Wt)[i] = ((const float4*)Wfc)[i];
    for (int i = threadIdx.x; i < 64 * 16; i += 256)
        ((float4*)Wc)[i] = ((const float4*)Wcomb)[i];
    for (int i = threadIdx.x; i < 1024; i += 256) {       // 16 rows x 64 uints
        int rr = i >> 6, uu = i & 63;
        int gr = r0 + rr;
        u32 u = 0;
        if (gr < M) u = ((const u32*)(S + (size_t)gr * 128))[uu];
        Ss[rr][uu * 2] = bflo(u);
        Ss[rr][uu * 2 + 1] = bfhi(u);
    }
    for (int i = threadIdx.x; i < 512; i += 256) {        // 16 rows x 32 uints
        int rr = i >> 5, uu = i & 31;
        int gr = r0 + rr;
        u32 u = 0;
        if (gr < M) u = ((const u32*)(Gg + (size_t)gr * 64))[uu];
        Gs[rr][uu * 2] = bflo(u);
        Gs[rr][uu * 2 + 1] = bfhi(u);
    }
    __syncthreads();
    int rl = threadIdx.x >> 4;
    int cg = threadIdx.x & 15;
    int r = r0 + rl;
    if (r >= M) return;
    float cnt = (float)(offm[r + 1] - offm[r]);
    float4 bv = ((const float4*)bvec)[cg];
    float4 bf = ((const float4*)bfc)[cg];
    float a0 = fmaf(cnt, bv.x, bf.x);
    float a1 = fmaf(cnt, bv.y, bf.y);
    float a2 = fmaf(cnt, bv.z, bf.z);
    float a3 = fmaf(cnt, bv.w, bf.w);
    #pragma unroll 4
    for (int k = 0; k < 128; k++) {
        float a = Ss[rl][k];
        float4 w = *(const float4*)(&Wt[k * 64 + cg * 4]);
        a0 = fmaf(a, w.x, a0); a1 = fmaf(a, w.y, a1);
        a2 = fmaf(a, w.z, a2); a3 = fmaf(a, w.w, a3);
    }
    #pragma unroll 4
    for (int k = 0; k < 64; k++) {
        float g = Gs[rl][k];
        float4 w = *(const float4*)(&Wc[k * 64 + cg * 4]);
        a0 = fmaf(g, w.x, a0); a1 = fmaf(g, w.y, a1);
        a2 = fmaf(g, w.z, a2); a3 = fmaf(g, w.w, a3);
    }
    ((float4*)(out + (size_t)r * 64))[cg] = make_float4(a0, a1, a2, a3);
}

extern "C" void kernel_launch(void* const* d_in, const int* in_sizes, int n_in,
                              void* d_out, int out_size, void* d_ws, size_t ws_size,
                              hipStream_t stream)
{
    const float* nf  = (const float*)d_in[0];
    const int*   ei  = (const int*)d_in[1];
    const float* ef  = (const float*)d_in[2];
    const int*   emi = (const int*)d_in[3];
    const float* W1  = (const float*)d_in[4];
    const float* b1  = (const float*)d_in[5];
    const float* W2  = (const float*)d_in[6];
    const float* b2  = (const float*)d_in[7];
    const float* We  = (const float*)d_in[8];
    const float* be  = (const float*)d_in[9];
    const float* Wfc = (const float*)d_in[10];
    const float* bfc = (const float*)d_in[11];

    const int* row  = ei;
    const int* col  = ei + N_EDGES;
    const int* mrow = emi;
    const int* mcol = emi + N_EDGES;

    // workspace: ping-pong bf16 node buffers A,B; S; Gg; then f32/int tables.
    u16* A  = (u16*)d_ws;                          // 50000*128 bf16
    u16* B  = A + (size_t)N_NODES * 128;           // 50000*128
    u16* S  = B + (size_t)N_NODES * 128;           // 50000*128
    u16* Gg = S + (size_t)N_NODES * 128;           // 50000*64
    float* Wcomb = (float*)(Gg + (size_t)N_NODES * 64);
    float* bvec  = Wcomb + 64 * 64;
    int* off  = (int*)(bvec + 64);                 // N+1
    int* pos  = off + (N_NODES + 1);
    int* offm = pos + N_NODES;                     // N+1
    int* posm = offm + (N_NODES + 1);
    int* cnt  = posm + N_NODES;                    // N } contiguous for scan
    int* cntm = cnt + N_NODES;                     // N }
    int* P    = cntm + N_NODES;
    int* Pex  = P + SCAN_BLOCKS;
    int* src_ids  = Pex + SCAN_BLOCKS;
    int* srcm_ids = src_ids + N_EDGES;

    (void)hipMemsetAsync(cnt, 0, 2 * (size_t)N_NODES * sizeof(int), stream);

    precompute_wcomb<<<17, 256, 0, stream>>>(We, be, Wfc, Wcomb, bvec);

    build_hist<<<(2 * N_EDGES + 255) / 256, 256, 0, stream>>>(col, mcol, cnt, cntm);
    scan_partials<<<SCAN_BLOCKS, 1024, 0, stream>>>(cnt, P);
    scan_mid<<<1, 64, 0, stream>>>(P, Pex, off, offm);
    scan_final<<<SCAN_BLOCKS, 1024, 0, stream>>>(cnt, Pex, off, pos, offm, posm);
    fill_csr<<<(2 * N_EDGES + 255) / 256, 256, 0, stream>>>(
        row, col, mrow, mcol, pos, posm, src_ids, srcm_ids);

    // P1 = nf @ W1  (bf16)
    gemm_f32_bf16<<<(N_NODES + 7) / 8, 256, 0, stream>>>(nf, W1, A, N_NODES);
    // x1 = relu(segsum(P1) + deg b1)
    agg_relu_bf16<<<(N_NODES + 3) / 4, 256, 0, stream>>>(A, off, src_ids, b1, B, N_NODES);
    // P2 = x1 @ W2
    gemm_bf16_bf16<<<(N_NODES + 7) / 8, 256, 0, stream>>>(B, W2, A, N_NODES);
    // x2 = relu(segsum(P2) + deg b2)
    agg_relu_bf16<<<(N_NODES + 3) / 4, 256, 0, stream>>>(A, off, src_ids, b2, B, N_NODES);
    // S = x2 + agg(x2); Gg = agg_m(ef)
    agg_epilogue<<<(N_NODES + 3) / 4, 256, 0, stream>>>(
        B, ef, off, src_ids, offm, srcm_ids, S, Gg, N_NODES);
    // out = S@Wfc_top + Gg@Wcomb + cnt bvec + bfc
    final_gemm<<<(N_NODES + 15) / 16, 256, 0, stream>>>(
        S, Gg, offm, Wfc, Wcomb, bvec, bfc, (float*)d_out, N_NODES);
}

// Round 6
// 722.507 us; speedup vs baseline: 7.1885x; 1.0535x over previous
//
#include <hip/hip_runtime.h>

#define N_NODES 50000
#define N_EDGES 800000
#define NODE_DIM 128
#define EDGE_DIM 64
#define HIDDEN 128
#define OUT_DIM 64
#define NCAT (2 * N_NODES)
#define SCAN_BLOCKS ((NCAT + 1023) / 1024)   // 98

typedef unsigned short u16;
typedef unsigned int u32;

__device__ __forceinline__ float bflo(u32 u) { return __builtin_bit_cast(float, u << 16); }
__device__ __forceinline__ float bfhi(u32 u) { return __builtin_bit_cast(float, u & 0xFFFF0000u); }
__device__ __forceinline__ u32 pack2(float x, float y) {
    u32 a = __builtin_bit_cast(u32, x);
    a += 0x7FFFu + ((a >> 16) & 1u);
    u32 b = __builtin_bit_cast(u32, y);
    b += 0x7FFFu + ((b >> 16) & 1u);
    return (a >> 16) | (b & 0xFFFF0000u);
}

// ---------------------------------------------------------------------------
// CSR build
// ---------------------------------------------------------------------------
__global__ __launch_bounds__(256) void build_hist(
    const int* __restrict__ col, const int* __restrict__ mcol,
    int* __restrict__ cnt, int* __restrict__ cntm, int* __restrict__ dcol)
{
    int idx = blockIdx.x * 256 + threadIdx.x;
    if (idx < N_EDGES) {
        atomicAdd(&cnt[col[idx]], 1);
    } else if (idx < 2 * N_EDGES) {
        int j = idx - N_EDGES;
        int d = col[mcol[j]];
        dcol[j] = d;
        atomicAdd(&cntm[d], 1);
    }
}

__global__ __launch_bounds__(1024) void scan_partials(
    const int* __restrict__ H, int* __restrict__ P)
{
    int t = blockIdx.x * 1024 + threadIdx.x;
    int v = (t < NCAT) ? H[t] : 0;
    for (int d = 1; d < 64; d <<= 1) v += __shfl_xor(v, d, 64);
    __shared__ int wsum[16];
    if ((threadIdx.x & 63) == 0) wsum[threadIdx.x >> 6] = v;
    __syncthreads();
    if (threadIdx.x == 0) {
        int s = 0;
        for (int i = 0; i < 16; i++) s += wsum[i];
        P[blockIdx.x] = s;
    }
}

__global__ void scan_mid(const int* __restrict__ P, int* __restrict__ Pex,
                         int* __restrict__ off, int* __restrict__ offm)
{
    if (threadIdx.x == 0) {
        int run = 0;
        for (int b = 0; b < SCAN_BLOCKS; b++) { Pex[b] = run; run += P[b]; }
        off[N_NODES] = N_EDGES;
        offm[N_NODES] = N_EDGES;
    }
}

__global__ __launch_bounds__(1024) void scan_final(
    const int* __restrict__ H, const int* __restrict__ Pex,
    int* __restrict__ off, int* __restrict__ pos,
    int* __restrict__ offm, int* __restrict__ posm)
{
    int t = blockIdx.x * 1024 + threadIdx.x;
    int lane = threadIdx.x & 63, wid = threadIdx.x >> 6;
    int v = (t < NCAT) ? H[t] : 0;
    int x = v;
    for (int d = 1; d < 64; d <<= 1) {
        int u = __shfl_up(x, d, 64);
        if (lane >= d) x += u;
    }
    __shared__ int wsum[16];
    __shared__ int wex[16];
    if (lane == 63) wsum[wid] = x;
    __syncthreads();
    if (threadIdx.x == 0) {
        int run = 0;
        for (int i = 0; i < 16; i++) { wex[i] = run; run += wsum[i]; }
    }
    __syncthreads();
    int excl = Pex[blockIdx.x] + wex[wid] + x - v;
    if (t < N_NODES) {
        off[t] = excl; pos[t] = excl;
    } else if (t < NCAT) {
        int u = t - N_NODES;
        offm[u] = excl - N_EDGES; posm[u] = excl - N_EDGES;
    }
}

__global__ __launch_bounds__(256) void fill_csr(
    const int* __restrict__ row, const int* __restrict__ col,
    const int* __restrict__ mrow, const int* __restrict__ dcol,
    int* __restrict__ pos, int* __restrict__ posm,
    int* __restrict__ src_ids, int* __restrict__ srcm_ids)
{
    int idx = blockIdx.x * 256 + threadIdx.x;
    if (idx < N_EDGES) {
        int p = atomicAdd(&pos[col[idx]], 1);
        src_ids[p] = row[idx];
    } else if (idx < 2 * N_EDGES) {
        int j = idx - N_EDGES;
        int p = atomicAdd(&posm[dcol[j]], 1);
        srcm_ids[p] = mrow[j];
    }
}

// ---------------------------------------------------------------------------
// Wcomb = We @ Wfc[128:256], bvec = be @ Wfc[128:256]
// ---------------------------------------------------------------------------
__global__ __launch_bounds__(256) void precompute_wcomb(
    const float* __restrict__ We, const float* __restrict__ be,
    const float* __restrict__ Wfc, float* __restrict__ Wcomb,
    float* __restrict__ bvec)
{
    int idx = blockIdx.x * 256 + threadIdx.x;
    if (idx < 64 * 64) {
        int k = idx >> 6, c = idx & 63;
        float s = 0.f;
        for (int h = 0; h < 128; h++)
            s = fmaf(We[k * 128 + h], Wfc[(128 + h) * 64 + c], s);
        Wcomb[idx] = s;
    } else if (idx < 64 * 64 + 64) {
        int c = idx - 64 * 64;
        float s = 0.f;
        for (int h = 0; h < 128; h++)
            s = fmaf(be[h], Wfc[(128 + h) * 64 + c], s);
        bvec[c] = s;
    }
}

// ---------------------------------------------------------------------------
// Micro-tiled GEMM, f32 A: P = A(Mx128) @ W(128x128) -> bf16.
// 64 rows/block, thread = 4 rows x 8 cols (cols cg*4 and 64+cg*4).
// ---------------------------------------------------------------------------
__global__ __launch_bounds__(256) void gemm64_f32(
    const float* __restrict__ A, const float* __restrict__ W,
    u16* __restrict__ P, int M)
{
    __shared__ float As[64][132];    // 33.8 KB, +4-bank row skew
    __shared__ float Ws[64][128];    // 32 KB
    int r0 = blockIdx.x * 64;
    for (int i = threadIdx.x; i < 64 * 32; i += 256) {
        int rr = i >> 5, cc = i & 31;
        int gr = r0 + rr;
        float4 v = make_float4(0.f, 0.f, 0.f, 0.f);
        if (gr < M) v = ((const float4*)(A + (size_t)gr * 128))[cc];
        *(float4*)(&As[rr][cc * 4]) = v;
    }
    float acc[4][8];
    #pragma unroll
    for (int r = 0; r < 4; r++)
        #pragma unroll
        for (int c = 0; c < 8; c++) acc[r][c] = 0.f;
    int rg = threadIdx.x >> 4;   // 0..15 -> rows rg*4..rg*4+3
    int cg = threadIdx.x & 15;   // cols cg*4..+3 and 64+cg*4..+3
    for (int kb = 0; kb < 2; kb++) {
        __syncthreads();
        for (int i = threadIdx.x; i < 64 * 32; i += 256) {
            int rr = i >> 5, cc = i & 31;
            *(float4*)(&Ws[rr][cc * 4]) =
                ((const float4*)(W + (size_t)(kb * 64 + rr) * 128))[cc];
        }
        __syncthreads();
        #pragma unroll 8
        for (int k = 0; k < 64; k++) {
            float4 w0 = *(const float4*)(&Ws[k][cg * 4]);
            float4 w1 = *(const float4*)(&Ws[k][64 + cg * 4]);
            #pragma unroll
            for (int r = 0; r < 4; r++) {
                float a = As[rg * 4 + r][kb * 64 + k];
                acc[r][0] = fmaf(a, w0.x, acc[r][0]);
                acc[r][1] = fmaf(a, w0.y, acc[r][1]);
                acc[r][2] = fmaf(a, w0.z, acc[r][2]);
                acc[r][3] = fmaf(a, w0.w, acc[r][3]);
                acc[r][4] = fmaf(a, w1.x, acc[r][4]);
                acc[r][5] = fmaf(a, w1.y, acc[r][5]);
                acc[r][6] = fmaf(a, w1.z, acc[r][6]);
                acc[r][7] = fmaf(a, w1.w, acc[r][7]);
            }
        }
    }
    #pragma unroll
    for (int r = 0; r < 4; r++) {
        int gr = r0 + rg * 4 + r;
        if (gr < M) {
            uint2 o0, o1;
            o0.x = pack2(acc[r][0], acc[r][1]);
            o0.y = pack2(acc[r][2], acc[r][3]);
            o1.x = pack2(acc[r][4], acc[r][5]);
            o1.y = pack2(acc[r][6], acc[r][7]);
            ((uint2*)(P + (size_t)gr * 128))[cg] = o0;
            ((uint2*)(P + (size_t)gr * 128 + 64))[cg] = o1;
        }
    }
}

// ---------------------------------------------------------------------------
// Micro-tiled GEMM, bf16 A: P = A(Mx128 bf16) @ W(128x128) -> bf16.
// ---------------------------------------------------------------------------
__global__ __launch_bounds__(256) void gemm64_bf16(
    const u16* __restrict__ A, const float* __restrict__ W,
    u16* __restrict__ P, int M)
{
    __shared__ float As[64][132];
    __shared__ float Ws[64][128];
    int r0 = blockIdx.x * 64;
    for (int i = threadIdx.x; i < 64 * 32; i += 256) {
        int rr = i >> 5, cc = i & 31;
        int gr = r0 + rr;
        uint2 u = make_uint2(0u, 0u);
        if (gr < M) u = ((const uint2*)(A + (size_t)gr * 128))[cc];
        float4 v = make_float4(bflo(u.x), bfhi(u.x), bflo(u.y), bfhi(u.y));
        *(float4*)(&As[rr][cc * 4]) = v;
    }
    float acc[4][8];
    #pragma unroll
    for (int r = 0; r < 4; r++)
        #pragma unroll
        for (int c = 0; c < 8; c++) acc[r][c] = 0.f;
    int rg = threadIdx.x >> 4;
    int cg = threadIdx.x & 15;
    for (int kb = 0; kb < 2; kb++) {
        __syncthreads();
        for (int i = threadIdx.x; i < 64 * 32; i += 256) {
            int rr = i >> 5, cc = i & 31;
            *(float4*)(&Ws[rr][cc * 4]) =
                ((const float4*)(W + (size_t)(kb * 64 + rr) * 128))[cc];
        }
        __syncthreads();
        #pragma unroll 8
        for (int k = 0; k < 64; k++) {
            float4 w0 = *(const float4*)(&Ws[k][cg * 4]);
            float4 w1 = *(const float4*)(&Ws[k][64 + cg * 4]);
            #pragma unroll
            for (int r = 0; r < 4; r++) {
                float a = As[rg * 4 + r][kb * 64 + k];
                acc[r][0] = fmaf(a, w0.x, acc[r][0]);
                acc[r][1] = fmaf(a, w0.y, acc[r][1]);
                acc[r][2] = fmaf(a, w0.z, acc[r][2]);
                acc[r][3] = fmaf(a, w0.w, acc[r][3]);
                acc[r][4] = fmaf(a, w1.x, acc[r][4]);
                acc[r][5] = fmaf(a, w1.y, acc[r][5]);
                acc[r][6] = fmaf(a, w1.z, acc[r][6]);
                acc[r][7] = fmaf(a, w1.w, acc[r][7]);
            }
        }
    }
    #pragma unroll
    for (int r = 0; r < 4; r++) {
        int gr = r0 + rg * 4 + r;
        if (gr < M) {
            uint2 o0, o1;
            o0.x = pack2(acc[r][0], acc[r][1]);
            o0.y = pack2(acc[r][2], acc[r][3]);
            o1.x = pack2(acc[r][4], acc[r][5]);
            o1.y = pack2(acc[r][6], acc[r][7]);
            ((uint2*)(P + (size_t)gr * 128))[cg] = o0;
            ((uint2*)(P + (size_t)gr * 128 + 64))[cg] = o1;
        }
    }
}

// ---------------------------------------------------------------------------
// X[w] = relu(segsum(P) + deg*bias). 1 node/wave; 16 lanes x uint4 per row;
// 4 quarters = 4 edges per load inst; 8 edges in flight per iter.
// ---------------------------------------------------------------------------
__global__ __launch_bounds__(256) void agg_relu_bf16(
    const u16* __restrict__ P, const int* __restrict__ off,
    const int* __restrict__ ids, const float* __restrict__ bias,
    u16* __restrict__ X, int M)
{
    int w = blockIdx.x * 4 + (threadIdx.x >> 6);
    if (w >= M) return;
    int lane = threadIdx.x & 63;
    int q = lane >> 4;
    int l = lane & 15;
    int beg = off[w], end = off[w + 1];
    const uint4* F = (const uint4*)P;   // 16 uint4 per row
    float a0 = 0.f, a1 = 0.f, a2 = 0.f, a3 = 0.f,
          a4 = 0.f, a5 = 0.f, a6 = 0.f, a7 = 0.f;
    int i = beg;
    for (; i + 7 < end; i += 8) {
        int s0 = ids[i + q], s1 = ids[i + q + 4];
        uint4 v0 = F[(size_t)s0 * 16 + l];
        uint4 v1 = F[(size_t)s1 * 16 + l];
        a0 += bflo(v0.x) + bflo(v1.x); a1 += bfhi(v0.x) + bfhi(v1.x);
        a2 += bflo(v0.y) + bflo(v1.y); a3 += bfhi(v0.y) + bfhi(v1.y);
        a4 += bflo(v0.z) + bflo(v1.z); a5 += bfhi(v0.z) + bfhi(v1.z);
        a6 += bflo(v0.w) + bflo(v1.w); a7 += bfhi(v0.w) + bfhi(v1.w);
    }
    for (int j = i + q; j < end; j += 4) {
        uint4 v = F[(size_t)ids[j] * 16 + l];
        a0 += bflo(v.x); a1 += bfhi(v.x);
        a2 += bflo(v.y); a3 += bfhi(v.y);
        a4 += bflo(v.z); a5 += bfhi(v.z);
        a6 += bflo(v.w); a7 += bfhi(v.w);
    }
    a0 += __shfl_xor(a0, 32, 64); a1 += __shfl_xor(a1, 32, 64);
    a2 += __shfl_xor(a2, 32, 64); a3 += __shfl_xor(a3, 32, 64);
    a4 += __shfl_xor(a4, 32, 64); a5 += __shfl_xor(a5, 32, 64);
    a6 += __shfl_xor(a6, 32, 64); a7 += __shfl_xor(a7, 32, 64);
    a0 += __shfl_xor(a0, 16, 64); a1 += __shfl_xor(a1, 16, 64);
    a2 += __shfl_xor(a2, 16, 64); a3 += __shfl_xor(a3, 16, 64);
    a4 += __shfl_xor(a4, 16, 64); a5 += __shfl_xor(a5, 16, 64);
    a6 += __shfl_xor(a6, 16, 64); a7 += __shfl_xor(a7, 16, 64);
    if (q == 0) {
        float dg = (float)(end - beg);
        float4 b0 = ((const float4*)bias)[2 * l];
        float4 b1 = ((const float4*)bias)[2 * l + 1];
        a0 = fmaxf(fmaf(dg, b0.x, a0), 0.f);
        a1 = fmaxf(fmaf(dg, b0.y, a1), 0.f);
        a2 = fmaxf(fmaf(dg, b0.z, a2), 0.f);
        a3 = fmaxf(fmaf(dg, b0.w, a3), 0.f);
        a4 = fmaxf(fmaf(dg, b1.x, a4), 0.f);
        a5 = fmaxf(fmaf(dg, b1.y, a5), 0.f);
        a6 = fmaxf(fmaf(dg, b1.z, a6), 0.f);
        a7 = fmaxf(fmaf(dg, b1.w, a7), 0.f);
        uint4 o;
        o.x = pack2(a0, a1); o.y = pack2(a2, a3);
        o.z = pack2(a4, a5); o.w = pack2(a6, a7);
        ((uint4*)(X + (size_t)w * 128))[l] = o;
    }
}

// ---------------------------------------------------------------------------
// Epilogue agg: S[w] = x2[w] + segsum(x2) (bf16); Gg[w] = segsum_m(ef) (bf16).
// ---------------------------------------------------------------------------
__global__ __launch_bounds__(256) void agg_epilogue(
    const u16* __restrict__ X2, const float* __restrict__ ef,
    const int* __restrict__ off, const int* __restrict__ ids,
    const int* __restrict__ offm, const int* __restrict__ mids,
    u16* __restrict__ S, u16* __restrict__ Gg, int M)
{
    int w = blockIdx.x * 4 + (threadIdx.x >> 6);
    if (w >= M) return;
    int lane = threadIdx.x & 63;
    int q = lane >> 4;
    int l = lane & 15;
    // ---- node gather over X2 ----
    {
        int beg = off[w], end = off[w + 1];
        const uint4* F = (const uint4*)X2;
        float a0 = 0.f, a1 = 0.f, a2 = 0.f, a3 = 0.f,
              a4 = 0.f, a5 = 0.f, a6 = 0.f, a7 = 0.f;
        int i = beg;
        for (; i + 7 < end; i += 8) {
            int s0 = ids[i + q], s1 = ids[i + q + 4];
            uint4 v0 = F[(size_t)s0 * 16 + l];
            uint4 v1 = F[(size_t)s1 * 16 + l];
            a0 += bflo(v0.x) + bflo(v1.x); a1 += bfhi(v0.x) + bfhi(v1.x);
            a2 += bflo(v0.y) + bflo(v1.y); a3 += bfhi(v0.y) + bfhi(v1.y);
            a4 += bflo(v0.z) + bflo(v1.z); a5 += bfhi(v0.z) + bfhi(v1.z);
            a6 += bflo(v0.w) + bflo(v1.w); a7 += bfhi(v0.w) + bfhi(v1.w);
        }
        for (int j = i + q; j < end; j += 4) {
            uint4 v = F[(size_t)ids[j] * 16 + l];
            a0 += bflo(v.x); a1 += bfhi(v.x);
            a2 += bflo(v.y); a3 += bfhi(v.y);
            a4 += bflo(v.z); a5 += bfhi(v.z);
            a6 += bflo(v.w); a7 += bfhi(v.w);
        }
        a0 += __shfl_xor(a0, 32, 64); a1 += __shfl_xor(a1, 32, 64);
        a2 += __shfl_xor(a2, 32, 64); a3 += __shfl_xor(a3, 32, 64);
        a4 += __shfl_xor(a4, 32, 64); a5 += __shfl_xor(a5, 32, 64);
        a6 += __shfl_xor(a6, 32, 64); a7 += __shfl_xor(a7, 32, 64);
        a0 += __shfl_xor(a0, 16, 64); a1 += __shfl_xor(a1, 16, 64);
        a2 += __shfl_xor(a2, 16, 64); a3 += __shfl_xor(a3, 16, 64);
        a4 += __shfl_xor(a4, 16, 64); a5 += __shfl_xor(a5, 16, 64);
        a6 += __shfl_xor(a6, 16, 64); a7 += __shfl_xor(a7, 16, 64);
        if (q == 0) {
            uint4 own = F[(size_t)w * 16 + l];
            a0 += bflo(own.x); a1 += bfhi(own.x);
            a2 += bflo(own.y); a3 += bfhi(own.y);
            a4 += bflo(own.z); a5 += bfhi(own.z);
            a6 += bflo(own.w); a7 += bfhi(own.w);
            uint4 o;
            o.x = pack2(a0, a1); o.y = pack2(a2, a3);
            o.z = pack2(a4, a5); o.w = pack2(a6, a7);
            ((uint4*)(S + (size_t)w * 128))[l] = o;
        }
    }
    // ---- meta gather over ef (64 f32 rows = 16 float4) ----
    {
        int beg = offm[w], end = offm[w + 1];
        const float4* E = (const float4*)ef;
        float g0 = 0.f, g1 = 0.f, g2 = 0.f, g3 = 0.f;
        int i = beg;
        for (; i + 7 < end; i += 8) {
            int s0 = mids[i + q], s1 = mids[i + q + 4];
            float4 v0 = E[(size_t)s0 * 16 + l];
            float4 v1 = E[(size_t)s1 * 16 + l];
            g0 += v0.x + v1.x; g1 += v0.y + v1.y;
            g2 += v0.z + v1.z; g3 += v0.w + v1.w;
        }
        for (int j = i + q; j < end; j += 4) {
            float4 v = E[(size_t)mids[j] * 16 + l];
            g0 += v.x; g1 += v.y; g2 += v.z; g3 += v.w;
        }
        g0 += __shfl_xor(g0, 32, 64); g1 += __shfl_xor(g1, 32, 64);
        g2 += __shfl_xor(g2, 32, 64); g3 += __shfl_xor(g3, 32, 64);
        g0 += __shfl_xor(g0, 16, 64); g1 += __shfl_xor(g1, 16, 64);
        g2 += __shfl_xor(g2, 16, 64); g3 += __shfl_xor(g3, 16, 64);
        if (q == 0) {
            uint2 o;
            o.x = pack2(g0, g1); o.y = pack2(g2, g3);
            ((uint2*)(Gg + (size_t)w * 64))[l] = o;
        }
    }
}

// ---------------------------------------------------------------------------
// out = S@Wfc_top + Gg@Wcomb + cnt⊗bvec + bfc. 64 rows/block, 4x4 tile/thread.
// ---------------------------------------------------------------------------
__global__ __launch_bounds__(256) void final_gemm(
    const u16* __restrict__ S, const u16* __restrict__ Gg,
    const int* __restrict__ offm, const float* __restrict__ Wfc,
    const float* __restrict__ Wcomb, const float* __restrict__ bvec,
    const float* __restrict__ bfc, float* __restrict__ out, int M)
{
    __shared__ float Ss[64][132];   // 33.8 KB
    __shared__ float Gs[64][68];    // 17.4 KB
    __shared__ float Ws[64][64];    // 16 KB, reused across 3 phases
    int r0 = blockIdx.x * 64;
    for (int i = threadIdx.x; i < 64 * 32; i += 256) {
        int rr = i >> 5, cc = i & 31;
        int gr = r0 + rr;
        uint2 u = make_uint2(0u, 0u);
        if (gr < M) u = ((const uint2*)(S + (size_t)gr * 128))[cc];
        float4 v = make_float4(bflo(u.x), bfhi(u.x), bflo(u.y), bfhi(u.y));
        *(float4*)(&Ss[rr][cc * 4]) = v;
    }
    for (int i = threadIdx.x; i < 64 * 16; i += 256) {
        int rr = i >> 4, cc = i & 15;
        int gr = r0 + rr;
        uint2 u = make_uint2(0u, 0u);
        if (gr < M) u = ((const uint2*)(Gg + (size_t)gr * 64))[cc];
        float4 v = make_float4(bflo(u.x), bfhi(u.x), bflo(u.y), bfhi(u.y));
        *(float4*)(&Gs[rr][cc * 4]) = v;
    }
    float acc[4][4];
    #pragma unroll
    for (int r = 0; r < 4; r++)
        #pragma unroll
        for (int c = 0; c < 4; c++) acc[r][c] = 0.f;
    int rg = threadIdx.x >> 4;
    int cg = threadIdx.x & 15;
    // phases 0,1: S @ Wfc_top (K=128 in two 64-chunks); phase 2: Gg @ Wcomb
    for (int ph = 0; ph < 3; ph++) {
        __syncthreads();
        const float* Wsrc = (ph < 2) ? (Wfc + (size_t)ph * 64 * 64) : Wcomb;
        for (int i = threadIdx.x; i < 64 * 16; i += 256) {
            int rr = i >> 4, cc = i & 15;
            *(float4*)(&Ws[rr][cc * 4]) = ((const float4*)(Wsrc + (size_t)rr * 64))[cc];
        }
        __syncthreads();
        #pragma unroll 8
        for (int k = 0; k < 64; k++) {
            float4 wv = *(const float4*)(&Ws[k][cg * 4]);
            #pragma unroll
            for (int r = 0; r < 4; r++) {
                float a = (ph < 2) ? Ss[rg * 4 + r][ph * 64 + k] : Gs[rg * 4 + r][k];
                acc[r][0] = fmaf(a, wv.x, acc[r][0]);
                acc[r][1] = fmaf(a, wv.y, acc[r][1]);
                acc[r][2] = fmaf(a, wv.z, acc[r][2]);
                acc[r][3] = fmaf(a, wv.w, acc[r][3]);
            }
        }
    }
    float4 bv = ((const float4*)bvec)[cg];
    float4 bf = ((const float4*)bfc)[cg];
    #pragma unroll
    for (int r = 0; r < 4; r++) {
        int gr = r0 + rg * 4 + r;
        if (gr < M) {
            float cnt = (float)(offm[gr + 1] - offm[gr]);
            float4 o;
            o.x = acc[r][0] + fmaf(cnt, bv.x, bf.x);
            o.y = acc[r][1] + fmaf(cnt, bv.y, bf.y);
            o.z = acc[r][2] + fmaf(cnt, bv.z, bf.z);
            o.w = acc[r][3] + fmaf(cnt, bv.w, bf.w);
            ((float4*)(out + (size_t)gr * 64))[cg] = o;
        }
    }
}

extern "C" void kernel_launch(void* const* d_in, const int* in_sizes, int n_in,
                              void* d_out, int out_size, void* d_ws, size_t ws_size,
                              hipStream_t stream)
{
    const float* nf  = (const float*)d_in[0];
    const int*   ei  = (const int*)d_in[1];
    const float* ef  = (const float*)d_in[2];
    const int*   emi = (const int*)d_in[3];
    const float* W1  = (const float*)d_in[4];
    const float* b1  = (const float*)d_in[5];
    const float* W2  = (const float*)d_in[6];
    const float* b2  = (const float*)d_in[7];
    const float* We  = (const float*)d_in[8];
    const float* be  = (const float*)d_in[9];
    const float* Wfc = (const float*)d_in[10];
    const float* bfc = (const float*)d_in[11];

    const int* row  = ei;
    const int* col  = ei + N_EDGES;
    const int* mrow = emi;
    const int* mcol = emi + N_EDGES;

    u16* A  = (u16*)d_ws;                          // 50000*128 bf16
    u16* B  = A + (size_t)N_NODES * 128;           // 50000*128
    u16* S  = B + (size_t)N_NODES * 128;           // 50000*128
    u16* Gg = S + (size_t)N_NODES * 128;           // 50000*64
    float* Wcomb = (float*)(Gg + (size_t)N_NODES * 64);
    float* bvec  = Wcomb + 64 * 64;
    int* off  = (int*)(bvec + 64);                 // N+1
    int* pos  = off + (N_NODES + 1);
    int* offm = pos + N_NODES;                     // N+1
    int* posm = offm + (N_NODES + 1);
    int* cnt  = posm + N_NODES;                    // N } contiguous for scan
    int* cntm = cnt + N_NODES;                     // N }
    int* P    = cntm + N_NODES;
    int* Pex  = P + SCAN_BLOCKS;
    int* src_ids  = Pex + SCAN_BLOCKS;             // N_EDGES
    int* srcm_ids = src_ids + N_EDGES;             // N_EDGES
    int* dcol     = srcm_ids + N_EDGES;            // N_EDGES

    (void)hipMemsetAsync(cnt, 0, 2 * (size_t)N_NODES * sizeof(int), stream);

    precompute_wcomb<<<17, 256, 0, stream>>>(We, be, Wfc, Wcomb, bvec);

    build_hist<<<(2 * N_EDGES + 255) / 256, 256, 0, stream>>>(col, mcol, cnt, cntm, dcol);
    scan_partials<<<SCAN_BLOCKS, 1024, 0, stream>>>(cnt, P);
    scan_mid<<<1, 64, 0, stream>>>(P, Pex, off, offm);
    scan_final<<<SCAN_BLOCKS, 1024, 0, stream>>>(cnt, Pex, off, pos, offm, posm);
    fill_csr<<<(2 * N_EDGES + 255) / 256, 256, 0, stream>>>(
        row, col, mrow, dcol, pos, posm, src_ids, srcm_ids);

    // P1 = nf @ W1 (bf16)
    gemm64_f32<<<(N_NODES + 63) / 64, 256, 0, stream>>>(nf, W1, A, N_NODES);
    // x1 = relu(segsum(P1) + deg b1)
    agg_relu_bf16<<<(N_NODES + 3) / 4, 256, 0, stream>>>(A, off, src_ids, b1, B, N_NODES);
    // P2 = x1 @ W2
    gemm64_bf16<<<(N_NODES + 63) / 64, 256, 0, stream>>>(B, W2, A, N_NODES);
    // x2 = relu(segsum(P2) + deg b2)
    agg_relu_bf16<<<(N_NODES + 3) / 4, 256, 0, stream>>>(A, off, src_ids, b2, B, N_NODES);
    // S = x2 + agg(x2); Gg = agg_m(ef)
    agg_epilogue<<<(N_NODES + 3) / 4, 256, 0, stream>>>(
        B, ef, off, src_ids, offm, srcm_ids, S, Gg, N_NODES);
    // out = S@Wfc_top + Gg@Wcomb + cnt bvec + bfc
    final_gemm<<<(N_NODES + 63) / 64, 256, 0, stream>>>(
        S, Gg, offm, Wfc, Wcomb, bvec, bfc, (float*)d_out, N_NODES);
}